// Round 8
// baseline (594.383 us; speedup 1.0000x reference)
//
#include <hip/hip_runtime.h>
#include <math.h>

// Problem constants
#define BB 16
#define CC 256
#define HH 128
#define WW 128
#define HWSZ 16384        // H*W
#define NF 8
#define EPSV 1e-5f

typedef __attribute__((ext_vector_type(8))) short short8;   // 8 bf16 = 4 VGPRs
typedef __attribute__((ext_vector_type(4))) float f32x4;

static __device__ __forceinline__ unsigned short f2bf(float f) {
  unsigned int u = __float_as_uint(f);
  u += 0x7fffu + ((u >> 16) & 1u);       // round-to-nearest-even
  return (unsigned short)(u >> 16);
}

static __device__ __forceinline__ float bf2f(unsigned int h) {
  return __uint_as_float(h << 16);
}

static __device__ __forceinline__ void gload_lds16(const unsigned short* g,
                                                   unsigned short* l) {
  __builtin_amdgcn_global_load_lds(
      (const __attribute__((address_space(1))) void*)(size_t)g,
      (__attribute__((address_space(3))) void*)(unsigned)(size_t)l, 16, 0, 0);
}

// ---------------------------------------------------------------------------
// K0: pack proj_w [o][c] fp32 -> bf16 in MFMA A-fragment order:
//     ap[((MB*8+kb)*64+lane)*8+e] = w[MB*16+(lane&15)][kb*32+(lane>>4)*8+e]
// ---------------------------------------------------------------------------
__global__ __launch_bounds__(256) void pack_a_kernel(
    const float* __restrict__ pw, unsigned short* __restrict__ ap) {
  int idx = blockIdx.x * 256 + threadIdx.x;     // 0..65535
  int e = idx & 7;
  int lane = (idx >> 3) & 63;
  int kb = (idx >> 9) & 7;
  int mb = idx >> 12;
  int o = mb * 16 + (lane & 15);
  int c = kb * 32 + (lane >> 4) * 8 + e;
  ap[idx] = f2bf(pw[o * 256 + c]);
}

// ---------------------------------------------------------------------------
// K1: pooled[b,c] = mean over HW.  One block per (b,c) plane.
// ---------------------------------------------------------------------------
__global__ __launch_bounds__(256) void pool_kernel(
    const float* __restrict__ x, float* __restrict__ pooled) {
  int plane = blockIdx.x;
  const float4* xp = (const float4*)(x + (size_t)plane * HWSZ);
  int tid = threadIdx.x;
  float s = 0.f;
#pragma unroll
  for (int i = 0; i < 16; ++i) {
    float4 v = xp[tid + i * 256];
    s += v.x + v.y + v.z + v.w;
  }
#pragma unroll
  for (int off = 32; off > 0; off >>= 1) s += __shfl_down(s, off, 64);
  __shared__ float ls[4];
  if ((tid & 63) == 0) ls[tid >> 6] = s;
  __syncthreads();
  if (tid == 0) pooled[plane] = (ls[0] + ls[1] + ls[2] + ls[3]) * (1.0f / 16384.0f);
}

// ---------------------------------------------------------------------------
// K2: selector: GAP -> linear -> softmax -> mix filter bank; zero GN stats.
// ---------------------------------------------------------------------------
__global__ __launch_bounds__(256) void selector_kernel(
    const float* __restrict__ pooled, const float* __restrict__ sel_w,
    const float* __restrict__ sel_b, const float* __restrict__ fbank,
    float* __restrict__ combined, float* __restrict__ stats) {
  int tid = threadIdx.x;
  stats[tid] = 0.f;  // 256 slots: [0..127] sum, [128..255] sumsq
  __shared__ float lg[BB][NF];
  __shared__ float wsm[BB][NF];
  if (tid < BB * NF) {
    int b = tid >> 3, n = tid & 7;
    const float* p = pooled + b * CC;
    const float* w = sel_w + n * CC;
    float d = sel_b[n];
    for (int c = 0; c < CC; c += 4) {
      d += p[c] * w[c] + p[c + 1] * w[c + 1] + p[c + 2] * w[c + 2] + p[c + 3] * w[c + 3];
    }
    lg[b][n] = d;
  }
  __syncthreads();
  if (tid < BB) {
    int b = tid;
    float m = lg[b][0];
#pragma unroll
    for (int n = 1; n < NF; ++n) m = fmaxf(m, lg[b][n]);
    float e[NF];
    float s = 0.f;
#pragma unroll
    for (int n = 0; n < NF; ++n) { e[n] = expf(lg[b][n] - m); s += e[n]; }
    float inv = 1.0f / s;
#pragma unroll
    for (int n = 0; n < NF; ++n) wsm[b][n] = e[n] * inv;
  }
  __syncthreads();
  for (int i = tid; i < BB * 49; i += 256) {
    int b = i / 49, j = i % 49;
    float acc = 0.f;
#pragma unroll
    for (int n = 0; n < NF; ++n) acc += wsm[b][n] * fbank[n * 49 + j];
    combined[b * 64 + j] = acc;
  }
}

// ---------------------------------------------------------------------------
// K3: depthwise 7x7 conv, per-sample filter; fp32 compute, bf16 output.
// ---------------------------------------------------------------------------
#define TR 32
__global__ __launch_bounds__(256) void dwconv_kernel(
    const float* __restrict__ x, const float* __restrict__ combined,
    unsigned short* __restrict__ fbp) {
  int plane = blockIdx.x;          // b*256 + c
  int rt = blockIdx.y;             // 0..3
  int b = plane >> 8;
  int r0 = rt * TR;
  int tid = threadIdx.x;

  __shared__ float xs[TR + 6][136];

  float kf[49];
  {
    const float* cb = combined + b * 64;
#pragma unroll
    for (int i = 0; i < 49; ++i) kf[i] = cb[i];
  }

  const size_t pbase = (size_t)plane * HWSZ;
  for (int idx = tid; idx < (TR + 6) * 34; idx += 256) {
    int row = idx / 34;
    int seg = idx % 34;
    int r = r0 - 3 + row;
    int c = seg * 4 - 4;
    float4 v = make_float4(0.f, 0.f, 0.f, 0.f);
    if (r >= 0 && r < HH && c >= 0 && c < WW) {
      v = *(const float4*)(x + pbase + (size_t)r * WW + c);
    }
    *(float4*)&xs[row][seg * 4] = v;
  }
  __syncthreads();

  int cg = tid & 31;
  int rg = tid >> 5;
  float acc[4][4] = {};

#pragma unroll
  for (int ri = 0; ri < 10; ++ri) {
    int lrow = 4 * rg + ri;
    float xr[12];
#pragma unroll
    for (int s = 0; s < 3; ++s)
      *(float4*)&xr[4 * s] = *(const float4*)&xs[lrow][cg * 4 + 4 * s];
#pragma unroll
    for (int orr = 0; orr < 4; ++orr) {
      int dy = ri - orr;
      if (dy < 0 || dy > 6) continue;
#pragma unroll
      for (int oc = 0; oc < 4; ++oc) {
#pragma unroll
        for (int dx = 0; dx < 7; ++dx) {
          acc[orr][oc] += xr[oc + dx + 1] * kf[dy * 7 + dx];
        }
      }
    }
  }

#pragma unroll
  for (int orr = 0; orr < 4; ++orr) {
    ushort4 sv;
    sv.x = f2bf(acc[orr][0]);
    sv.y = f2bf(acc[orr][1]);
    sv.z = f2bf(acc[orr][2]);
    sv.w = f2bf(acc[orr][3]);
    *(ushort4*)(fbp + pbase + (size_t)(r0 + 4 * rg + orr) * WW + 4 * cg) = sv;
  }
}

// ---------------------------------------------------------------------------
// K3.5: transpose fb[b][c][p] -> fbT[b][p][c].  Tile = 64c x 64p, 256 thr.
//       (proven round 5)
// ---------------------------------------------------------------------------
__global__ __launch_bounds__(256) void transpose_kernel(
    const unsigned short* __restrict__ fb, unsigned short* __restrict__ fbT) {
  int bid = blockIdx.x;            // 16 b * 4 cstripe * 256 pstripe
  int bs = bid >> 10;
  int cs = (bid >> 8) & 3;
  int ps = bid & 255;
  int t = threadIdx.x;

  __shared__ unsigned int Ts[64][33];

  int cpair = t >> 3;              // 0..31 -> c rows {2cp, 2cp+1}
  int pch = t & 7;                 // 0..7  -> p chunk of 8
  const unsigned short* s =
      fb + ((size_t)bs * CC + cs * 64 + 2 * cpair) * HWSZ + ps * 64 + pch * 8;
  uint4 A0 = *(const uint4*)s;
  uint4 A1 = *(const uint4*)(s + HWSZ);
  unsigned int wa[4] = {A0.x, A0.y, A0.z, A0.w};
  unsigned int wb[4] = {A1.x, A1.y, A1.z, A1.w};
#pragma unroll
  for (int i = 0; i < 8; ++i) {
    int p = pch * 8 + i;
    unsigned int lo = (wa[i >> 1] >> ((i & 1) * 16)) & 0xffffu;
    unsigned int hi = (wb[i >> 1] >> ((i & 1) * 16)) & 0xffffu;
    Ts[p][cpair] = lo | (hi << 16);
  }
  __syncthreads();

  size_t obase = ((size_t)bs * HWSZ + (size_t)ps * 64) * 256 + cs * 64;
#pragma unroll
  for (int r = 0; r < 2; ++r) {
    int chunk = t + 256 * r;
    int p = chunk >> 3, ch = chunk & 7;   // row p, c-chunk of 8 (4 uints)
    uint4 v;
    v.x = Ts[p][ch * 4];
    v.y = Ts[p][ch * 4 + 1];
    v.z = Ts[p][ch * 4 + 2];
    v.w = Ts[p][ch * 4 + 3];
    *(uint4*)(fbT + obase + (size_t)p * 256 + ch * 8) = v;
  }
}

// ---------------------------------------------------------------------------
// K4: 1x1 conv as bf16 MFMA GEMM:
//     y[b,o,p] = sum_c W[o][c]*F[b][c][p] + pb[o]
//     Block = 256 o x 64 p, 512 thr (8 waves, each 32o x 64p = 2x4 MFMA).
//     B panel (64p x 256c = 32KB) staged once via global_load_lds (r6-proven
//     mapping); single vmcnt(0)+barrier, then 8 BARRIER-FREE phases.
//     A-frags: depth-2 register rotation af[2][2] (16 VGPRs), per-phase
//     C-level loads -> compiler-managed waitcnt, no whole-loop preload
//     (r6's af[2][8] preload spilled to scratch: VGPR_Count=60 < 64 needed).
//     sched_barrier(0) per phase stops cross-phase load hoisting.
// ---------------------------------------------------------------------------
#define SWZ(p) ((((p) >> 1) ^ ((p) >> 4)) & 3)

__global__ __launch_bounds__(512, 2) void gemm_kernel(
    const unsigned short* __restrict__ fbT, const unsigned short* __restrict__ ap,
    const float* __restrict__ proj_b, unsigned short* __restrict__ yb,
    float* __restrict__ stats) {
  int bid = blockIdx.x;
  int bs = bid >> 8;               // sample
  int pt = bid & 255;              // pixel tile (64 wide)
  int p0 = pt * 64;
  int tid = threadIdx.x;
  int lane = tid & 63;
  int wave = tid >> 6;             // 0..7 -> o rows wave*32..+31

  // union: B panel 8 x [64p][32c] bf16 = 32 KB, then yt bounce 8x32x72x2 = 36.9 KB
  __shared__ __align__(16) unsigned char smem[8 * 32 * 72 * 2];
  unsigned short* Bp = (unsigned short*)smem;

  // --- staging mapping (r6-proven; rule #21: linear dest, inv-swizzled src)
  int half = tid >> 8;             // waves 0-3: even subtiles; 4-7: odd
  int t = tid & 255;
  int sp = t >> 2;
  int sj = (t & 3) ^ SWZ(sp);
  const unsigned short* bsrc =
      fbT + ((size_t)bs * HWSZ + p0 + sp) * 256 + sj * 8;
  unsigned short* bdst = Bp + (size_t)t * 8;

#pragma unroll
  for (int s = 0; s < 4; ++s) {
    int sub = 2 * s + half;
    gload_lds16(bsrc + sub * 32, bdst + (size_t)sub * 2048);
  }

  // --- A: depth-2 rotation, loads tracked by compiler
  const unsigned short* apl = ap + (size_t)(wave * 2) * 4096 + lane * 8;
  short8 af[2][2];
  af[0][0] = *(const short8*)(apl);                 // A(kb=0), mb=0
  af[0][1] = *(const short8*)(apl + 4096);          // A(kb=0), mb=1
  af[1][0] = *(const short8*)(apl + 512);           // A(kb=1), mb=0
  af[1][1] = *(const short8*)(apl + 4096 + 512);    // A(kb=1), mb=1

  f32x4 acc[2][4];
#pragma unroll
  for (int mb = 0; mb < 2; ++mb)
#pragma unroll
    for (int nb = 0; nb < 4; ++nb) acc[mb][nb] = (f32x4){0.f, 0.f, 0.f, 0.f};

  // LDS read offsets (elements), r4-proven swizzled mapping
  int pofs[4], cofs[4];
#pragma unroll
  for (int nb = 0; nb < 4; ++nb) {
    int pp = nb * 16 + (lane & 15);
    pofs[nb] = pp * 32;
    cofs[nb] = ((lane >> 4) * 8) ^ (SWZ(pp) << 3);
  }

  // single drain + single barrier: every wave's own B-gloads done => whole
  // panel staged (all waves pass barrier only after their own vmcnt(0)).
  asm volatile("s_waitcnt vmcnt(0)" ::: "memory");
  __builtin_amdgcn_s_barrier();

  // 8 barrier-free phases; panel is read-only
#pragma unroll
  for (int kb = 0; kb < 8; ++kb) {
    const unsigned short* Bk = Bp + kb * 2048;
    short8 bfr[4];
#pragma unroll
    for (int nb = 0; nb < 4; ++nb)
      bfr[nb] = *(const short8*)(Bk + pofs[nb] + cofs[nb]);
#pragma unroll
    for (int mb = 0; mb < 2; ++mb)
#pragma unroll
      for (int nb = 0; nb < 4; ++nb)
        acc[mb][nb] = __builtin_amdgcn_mfma_f32_16x16x32_bf16(
            af[kb & 1][mb], bfr[nb], acc[mb][nb], 0, 0, 0);
    if (kb < 6) {   // rotate: slot (kb&1) now holds A(kb+2)
      af[kb & 1][0] = *(const short8*)(apl + (kb + 2) * 512);
      af[kb & 1][1] = *(const short8*)(apl + 4096 + (kb + 2) * 512);
    }
    __builtin_amdgcn_sched_barrier(0);   // keep rotation depth-2 (no hoist)
  }

  __syncthreads();   // all waves done with panel: reuse LDS as bounce

  // ---- epilogue: bias, GN partial sums, bounce, coalesced stores
  // C/D layout: col(p) = lane&15, row(o) = (lane>>4)*4 + reg
  unsigned short* yt = (unsigned short*)smem + (size_t)wave * (32 * 72);
  float psum = 0.f, psq = 0.f;
  int orl = (lane >> 4) * 4;
  int pl = lane & 15;
#pragma unroll
  for (int mb = 0; mb < 2; ++mb) {
#pragma unroll
    for (int r = 0; r < 4; ++r) {
      int ol = mb * 16 + orl + r;
      float pb = proj_b[wave * 32 + ol];
#pragma unroll
      for (int nb = 0; nb < 4; ++nb) {
        float v = acc[mb][nb][r] + pb;
        yt[ol * 72 + pl + nb * 16] = f2bf(v);
        psum += v;
        psq += v * v;
      }
    }
  }
  // wave-private bounce: same-wave ds_write->ds_read ordered by lgkmcnt
  const size_t ybase = (size_t)bs * CC * HWSZ + p0;
#pragma unroll
  for (int k = 0; k < 4; ++k) {
    int idx = k * 64 + lane;
    int ol = idx >> 3, ch = idx & 7;
    uint4 v = *(const uint4*)(yt + ol * 72 + ch * 8);
    *(uint4*)(yb + ybase + (size_t)(wave * 32 + ol) * HWSZ + ch * 8) = v;
  }

#pragma unroll
  for (int off = 32; off > 0; off >>= 1) {
    psum += __shfl_down(psum, off, 64);
    psq += __shfl_down(psq, off, 64);
  }
  if (lane == 0) {
    int gb = bs * 8 + wave;        // wave covers exactly one GN group (32 ch)
    atomicAdd(&stats[gb], psum);
    atomicAdd(&stats[128 + gb], psq);
  }
}

// ---------------------------------------------------------------------------
// K5: GroupNorm affine + exact GELU + residual. Reads bf16 y, writes fp32 out.
// ---------------------------------------------------------------------------
__global__ __launch_bounds__(256) void out_kernel(
    const float* __restrict__ x, const unsigned short* __restrict__ yb,
    const float* __restrict__ stats, const float* __restrict__ gamma,
    const float* __restrict__ beta, float* __restrict__ out) {
  int plane = blockIdx.x;
  int b = plane >> 8, c = plane & 255, g = c >> 5;
  const float inv_n = 1.0f / (32.0f * (float)HWSZ);
  float mean = stats[b * 8 + g] * inv_n;
  float var = stats[128 + b * 8 + g] * inv_n - mean * mean;
  float rstd = rsqrtf(var + EPSV);
  float scale = gamma[c] * rstd;
  float shift = beta[c] - mean * scale;

  const size_t base = (size_t)plane * HWSZ;
  for (int i = threadIdx.x; i < HWSZ / 8; i += 256) {
    uint4 yv = *(const uint4*)(yb + base + 8 * (size_t)i);
    float4 x0 = *(const float4*)(x + base + 8 * (size_t)i);
    float4 x1 = *(const float4*)(x + base + 8 * (size_t)i + 4);
    unsigned int yw[4] = {yv.x, yv.y, yv.z, yv.w};
    float r[8];
    float xr[8] = {x0.x, x0.y, x0.z, x0.w, x1.x, x1.y, x1.z, x1.w};
#pragma unroll
    for (int k = 0; k < 8; ++k) {
      unsigned int h = (yw[k >> 1] >> ((k & 1) * 16)) & 0xffffu;
      float t = bf2f(h) * scale + shift;
      float ge = 0.5f * t * (1.0f + erff(t * 0.70710678118654752f));
      r[k] = ge + xr[k];
    }
    *(float4*)(out + base + 8 * (size_t)i) = make_float4(r[0], r[1], r[2], r[3]);
    *(float4*)(out + base + 8 * (size_t)i + 4) = make_float4(r[4], r[5], r[6], r[7]);
  }
}

// ---------------------------------------------------------------------------
extern "C" void kernel_launch(void* const* d_in, const int* in_sizes, int n_in,
                              void* d_out, int out_size, void* d_ws, size_t ws_size,
                              hipStream_t stream) {
  const float* x      = (const float*)d_in[0];
  const float* fbank  = (const float*)d_in[1];   // [NF,1,7,7]
  const float* sel_w  = (const float*)d_in[2];   // [NF,C]
  const float* sel_b  = (const float*)d_in[3];   // [NF]
  const float* proj_w = (const float*)d_in[4];   // [C,C,1,1]
  const float* proj_b = (const float*)d_in[5];   // [C]
  const float* gamma  = (const float*)d_in[6];   // [C]
  const float* beta   = (const float*)d_in[7];   // [C]
  float* out = (float*)d_out;

  // ws layout: buf0 bf16 [B*C*HW] (fb, later reused as yb) |
  //            buf1 bf16 [B*C*HW] (fbT) | ap bf16 [65536] | f32 smalls
  unsigned short* fb  = (unsigned short*)d_ws;   // dwconv out; dead after transpose
  unsigned short* yb  = fb;                      // gemm y output reuses fb space
  unsigned short* fbT = fb + (size_t)BB * CC * HWSZ;
  unsigned short* apk = fbT + (size_t)BB * CC * HWSZ;
  float* pooled   = (float*)(apk + 65536);
  float* combined = pooled + BB * CC;
  float* stats    = combined + BB * 64;

  hipLaunchKernelGGL(pack_a_kernel, dim3(256), dim3(256), 0, stream, proj_w, apk);
  hipLaunchKernelGGL(pool_kernel, dim3(BB * CC), dim3(256), 0, stream, x, pooled);
  hipLaunchKernelGGL(selector_kernel, dim3(1), dim3(256), 0, stream,
                     pooled, sel_w, sel_b, fbank, combined, stats);
  hipLaunchKernelGGL(dwconv_kernel, dim3(BB * CC, HH / TR), dim3(256), 0, stream,
                     x, combined, fb);
  hipLaunchKernelGGL(transpose_kernel, dim3(BB * 4 * 256), dim3(256), 0, stream,
                     fb, fbT);
  hipLaunchKernelGGL(gemm_kernel, dim3(BB * 256), dim3(512), 0, stream,
                     fbT, apk, proj_b, yb, stats);
  hipLaunchKernelGGL(out_kernel, dim3(BB * CC), dim3(256), 0, stream,
                     x, yb, stats, gamma, beta, out);
}

// Round 10
// 456.368 us; speedup vs baseline: 1.3024x; 1.3024x over previous
//
#include <hip/hip_runtime.h>
#include <math.h>

// Problem constants
#define BB 16
#define CC 256
#define HH 128
#define WW 128
#define HWSZ 16384        // H*W
#define NF 8
#define EPSV 1e-5f

typedef __attribute__((ext_vector_type(8))) short short8;   // 8 bf16 = 4 VGPRs
typedef __attribute__((ext_vector_type(4))) float f32x4;

static __device__ __forceinline__ unsigned short f2bf(float f) {
  unsigned int u = __float_as_uint(f);
  u += 0x7fffu + ((u >> 16) & 1u);       // round-to-nearest-even
  return (unsigned short)(u >> 16);
}

static __device__ __forceinline__ float bf2f(unsigned int h) {
  return __uint_as_float(h << 16);
}

static __device__ __forceinline__ void gload_lds16(const unsigned short* g,
                                                   unsigned short* l) {
  __builtin_amdgcn_global_load_lds(
      (const __attribute__((address_space(1))) void*)(size_t)g,
      (__attribute__((address_space(3))) void*)(unsigned)(size_t)l, 16, 0, 0);
}

// ---------------------------------------------------------------------------
// K0: pack proj_w [o][c] fp32 -> bf16 in MFMA A-fragment order:
//     ap[((MB*8+kb)*64+lane)*8+e] = w[MB*16+(lane&15)][kb*32+(lane>>4)*8+e]
// ---------------------------------------------------------------------------
__global__ __launch_bounds__(256) void pack_a_kernel(
    const float* __restrict__ pw, unsigned short* __restrict__ ap) {
  int idx = blockIdx.x * 256 + threadIdx.x;     // 0..65535
  int e = idx & 7;
  int lane = (idx >> 3) & 63;
  int kb = (idx >> 9) & 7;
  int mb = idx >> 12;
  int o = mb * 16 + (lane & 15);
  int c = kb * 32 + (lane >> 4) * 8 + e;
  ap[idx] = f2bf(pw[o * 256 + c]);
}

// ---------------------------------------------------------------------------
// K1: pooled[b,c] = mean over HW.  One block per (b,c) plane.
// ---------------------------------------------------------------------------
__global__ __launch_bounds__(256) void pool_kernel(
    const float* __restrict__ x, float* __restrict__ pooled) {
  int plane = blockIdx.x;
  const float4* xp = (const float4*)(x + (size_t)plane * HWSZ);
  int tid = threadIdx.x;
  float s = 0.f;
#pragma unroll
  for (int i = 0; i < 16; ++i) {
    float4 v = xp[tid + i * 256];
    s += v.x + v.y + v.z + v.w;
  }
#pragma unroll
  for (int off = 32; off > 0; off >>= 1) s += __shfl_down(s, off, 64);
  __shared__ float ls[4];
  if ((tid & 63) == 0) ls[tid >> 6] = s;
  __syncthreads();
  if (tid == 0) pooled[plane] = (ls[0] + ls[1] + ls[2] + ls[3]) * (1.0f / 16384.0f);
}

// ---------------------------------------------------------------------------
// K2: selector: GAP -> linear -> softmax -> mix filter bank.
// ---------------------------------------------------------------------------
__global__ __launch_bounds__(256) void selector_kernel(
    const float* __restrict__ pooled, const float* __restrict__ sel_w,
    const float* __restrict__ sel_b, const float* __restrict__ fbank,
    float* __restrict__ combined) {
  int tid = threadIdx.x;
  __shared__ float lg[BB][NF];
  __shared__ float wsm[BB][NF];
  if (tid < BB * NF) {
    int b = tid >> 3, n = tid & 7;
    const float* p = pooled + b * CC;
    const float* w = sel_w + n * CC;
    float d = sel_b[n];
    for (int c = 0; c < CC; c += 4) {
      d += p[c] * w[c] + p[c + 1] * w[c + 1] + p[c + 2] * w[c + 2] + p[c + 3] * w[c + 3];
    }
    lg[b][n] = d;
  }
  __syncthreads();
  if (tid < BB) {
    int b = tid;
    float m = lg[b][0];
#pragma unroll
    for (int n = 1; n < NF; ++n) m = fmaxf(m, lg[b][n]);
    float e[NF];
    float s = 0.f;
#pragma unroll
    for (int n = 0; n < NF; ++n) { e[n] = expf(lg[b][n] - m); s += e[n]; }
    float inv = 1.0f / s;
#pragma unroll
    for (int n = 0; n < NF; ++n) wsm[b][n] = e[n] * inv;
  }
  __syncthreads();
  for (int i = tid; i < BB * 49; i += 256) {
    int b = i / 49, j = i % 49;
    float acc = 0.f;
#pragma unroll
    for (int n = 0; n < NF; ++n) acc += wsm[b][n] * fbank[n * 49 + j];
    combined[b * 64 + j] = acc;
  }
}

// ---------------------------------------------------------------------------
// K3: depthwise 7x7 conv, per-sample filter; fp32 compute, bf16 output.
// ---------------------------------------------------------------------------
#define TR 32
__global__ __launch_bounds__(256) void dwconv_kernel(
    const float* __restrict__ x, const float* __restrict__ combined,
    unsigned short* __restrict__ fbp) {
  int plane = blockIdx.x;          // b*256 + c
  int rt = blockIdx.y;             // 0..3
  int b = plane >> 8;
  int r0 = rt * TR;
  int tid = threadIdx.x;

  __shared__ float xs[TR + 6][136];

  float kf[49];
  {
    const float* cb = combined + b * 64;
#pragma unroll
    for (int i = 0; i < 49; ++i) kf[i] = cb[i];
  }

  const size_t pbase = (size_t)plane * HWSZ;
  for (int idx = tid; idx < (TR + 6) * 34; idx += 256) {
    int row = idx / 34;
    int seg = idx % 34;
    int r = r0 - 3 + row;
    int c = seg * 4 - 4;
    float4 v = make_float4(0.f, 0.f, 0.f, 0.f);
    if (r >= 0 && r < HH && c >= 0 && c < WW) {
      v = *(const float4*)(x + pbase + (size_t)r * WW + c);
    }
    *(float4*)&xs[row][seg * 4] = v;
  }
  __syncthreads();

  int cg = tid & 31;
  int rg = tid >> 5;
  float acc[4][4] = {};

#pragma unroll
  for (int ri = 0; ri < 10; ++ri) {
    int lrow = 4 * rg + ri;
    float xr[12];
#pragma unroll
    for (int s = 0; s < 3; ++s)
      *(float4*)&xr[4 * s] = *(const float4*)&xs[lrow][cg * 4 + 4 * s];
#pragma unroll
    for (int orr = 0; orr < 4; ++orr) {
      int dy = ri - orr;
      if (dy < 0 || dy > 6) continue;
#pragma unroll
      for (int oc = 0; oc < 4; ++oc) {
#pragma unroll
        for (int dx = 0; dx < 7; ++dx) {
          acc[orr][oc] += xr[oc + dx + 1] * kf[dy * 7 + dx];
        }
      }
    }
  }

#pragma unroll
  for (int orr = 0; orr < 4; ++orr) {
    ushort4 sv;
    sv.x = f2bf(acc[orr][0]);
    sv.y = f2bf(acc[orr][1]);
    sv.z = f2bf(acc[orr][2]);
    sv.w = f2bf(acc[orr][3]);
    *(ushort4*)(fbp + pbase + (size_t)(r0 + 4 * rg + orr) * WW + 4 * cg) = sv;
  }
}

// ---------------------------------------------------------------------------
// K3.5: transpose fb[b][c][p] -> fbT[b][p][c].  (proven round 5)
// ---------------------------------------------------------------------------
__global__ __launch_bounds__(256) void transpose_kernel(
    const unsigned short* __restrict__ fb, unsigned short* __restrict__ fbT) {
  int bid = blockIdx.x;            // 16 b * 4 cstripe * 256 pstripe
  int bs = bid >> 10;
  int cs = (bid >> 8) & 3;
  int ps = bid & 255;
  int t = threadIdx.x;

  __shared__ unsigned int Ts[64][33];

  int cpair = t >> 3;              // 0..31 -> c rows {2cp, 2cp+1}
  int pch = t & 7;                 // 0..7  -> p chunk of 8
  const unsigned short* s =
      fb + ((size_t)bs * CC + cs * 64 + 2 * cpair) * HWSZ + ps * 64 + pch * 8;
  uint4 A0 = *(const uint4*)s;
  uint4 A1 = *(const uint4*)(s + HWSZ);
  unsigned int wa[4] = {A0.x, A0.y, A0.z, A0.w};
  unsigned int wb[4] = {A1.x, A1.y, A1.z, A1.w};
#pragma unroll
  for (int i = 0; i < 8; ++i) {
    int p = pch * 8 + i;
    unsigned int lo = (wa[i >> 1] >> ((i & 1) * 16)) & 0xffffu;
    unsigned int hi = (wb[i >> 1] >> ((i & 1) * 16)) & 0xffffu;
    Ts[p][cpair] = lo | (hi << 16);
  }
  __syncthreads();

  size_t obase = ((size_t)bs * HWSZ + (size_t)ps * 64) * 256 + cs * 64;
#pragma unroll
  for (int r = 0; r < 2; ++r) {
    int chunk = t + 256 * r;
    int p = chunk >> 3, ch = chunk & 7;   // row p, c-chunk of 8 (4 uints)
    uint4 v;
    v.x = Ts[p][ch * 4];
    v.y = Ts[p][ch * 4 + 1];
    v.z = Ts[p][ch * 4 + 2];
    v.w = Ts[p][ch * 4 + 3];
    *(uint4*)(fbT + obase + (size_t)p * 256 + ch * 8) = v;
  }
}

// ---------------------------------------------------------------------------
// K4: 1x1 conv as bf16 MFMA GEMM — streamed A+B with counted vmcnt (T3/T4):
//     Block = 128 o x 128 p, 512 thr (8 waves = 2 wm x 4 wn, each 64o x 32p).
//     Per K-step (32c): A-panel 8KB + B-panel 8KB staged via global_load_lds,
//     double-buffered, issued 2-ahead; s_waitcnt vmcnt(2) (never 0 mid-loop).
//     A-frags read from LDS (ds_read) -> the vm queue holds ONLY the counted
//     panel gloads (deterministic). GN partials to global (no atomics).
// ---------------------------------------------------------------------------
#define SWZ(p) ((((p) >> 1) ^ ((p) >> 4)) & 3)

__global__ __launch_bounds__(512, 4) void gemm_kernel(
    const unsigned short* __restrict__ fbT, const unsigned short* __restrict__ ap,
    const float* __restrict__ proj_b, unsigned short* __restrict__ yb,
    float* __restrict__ part) {
  int bid = blockIdx.x;            // (bs*2 + ot)*128 + pt
  int bs = bid >> 8;
  int ot = (bid >> 7) & 1;
  int pt = bid & 127;
  int p0 = pt * 128;
  int tid = threadIdx.x;
  int lane = tid & 63;
  int wave = tid >> 6;
  int wm = wave >> 2;              // 0..1 -> o 64-block
  int wn = wave & 3;               // 0..3 -> p 32-block

  __shared__ __align__(16) unsigned short A_lds[2][4096];  // [buf][MBl*512+lane*8]
  __shared__ __align__(16) unsigned short B_lds[2][4096];  // [buf][p*32 + c-swz]

  // --- staging sources (per-thread, one 16B gload each per panel)
  // A: linear copy of ap region for (ot*8 + t>>6, kb)
  const unsigned short* asrc0 =
      ap + (((size_t)(ot * 8 + (tid >> 6)) * 8) * 64 + (tid & 63)) * 8;
  unsigned short* adst = &A_lds[0][0] + (size_t)tid * 8;
  // B: fbT[bs][p0 + sp][kb*32 + sj*8], sj pre-XOR'd (rule #21)
  int sp = tid >> 2;
  int sj = (tid & 3) ^ SWZ(sp);
  const unsigned short* bsrc0 =
      fbT + ((size_t)bs * HWSZ + p0 + sp) * 256 + sj * 8;
  unsigned short* bdst = &B_lds[0][0] + (size_t)tid * 8;

#define STAGE(kb, buf)                                                  \
  do {                                                                  \
    gload_lds16(asrc0 + (size_t)(kb) * 512, adst + (size_t)(buf) * 4096); \
    gload_lds16(bsrc0 + (size_t)(kb) * 32, bdst + (size_t)(buf) * 4096);  \
  } while (0)

  // prologue: panels 0,1 in flight (4 gloads)
  STAGE(0, 0);
  STAGE(1, 1);

  f32x4 acc[4][2];
#pragma unroll
  for (int mb = 0; mb < 4; ++mb)
#pragma unroll
    for (int nb = 0; nb < 2; ++nb) acc[mb][nb] = (f32x4){0.f, 0.f, 0.f, 0.f};

  // LDS read offsets
  int aofs[4];
#pragma unroll
  for (int mb = 0; mb < 4; ++mb) aofs[mb] = ((wm * 4 + mb) * 64 + lane) * 8;
  int bofs[2];
#pragma unroll
  for (int nb = 0; nb < 2; ++nb) {
    int pp = wn * 32 + nb * 16 + (lane & 15);
    bofs[nb] = pp * 32 + (((lane >> 4) * 8) ^ (SWZ(pp) << 3));
  }

#pragma unroll
  for (int kb = 0; kb < 8; ++kb) {
    const int cur = kb & 1;
    if (kb < 7) {
      asm volatile("s_waitcnt vmcnt(2)" ::: "memory");  // panel kb done; kb+1 flying
    } else {
      asm volatile("s_waitcnt vmcnt(0)" ::: "memory");
    }
    __builtin_amdgcn_s_barrier();

    short8 af[4], bfr[2];
#pragma unroll
    for (int mb = 0; mb < 4; ++mb)
      af[mb] = *(const short8*)(&A_lds[cur][0] + aofs[mb]);
#pragma unroll
    for (int nb = 0; nb < 2; ++nb)
      bfr[nb] = *(const short8*)(&B_lds[cur][0] + bofs[nb]);
    asm volatile("s_waitcnt lgkmcnt(0)" ::: "memory");
    __builtin_amdgcn_sched_barrier(0);
    __builtin_amdgcn_s_barrier();            // all waves done reading cur bufs

    if (kb < 6) STAGE(kb + 2, cur);          // refill cur; flies during MFMAs
    __builtin_amdgcn_sched_barrier(0);

#pragma unroll
    for (int mb = 0; mb < 4; ++mb)
#pragma unroll
      for (int nb = 0; nb < 2; ++nb)
        acc[mb][nb] = __builtin_amdgcn_mfma_f32_16x16x32_bf16(
            af[mb], bfr[nb], acc[mb][nb], 0, 0, 0);
  }

  // ---- epilogue: bias, y store (bf16), GN partials (no atomics)
  // C/D layout: col(p) = lane&15, row(o) = (lane>>4)*4 + reg
  float psum[2] = {0.f, 0.f}, psq[2] = {0.f, 0.f};
  int orl = (lane >> 4) * 4;
  int pl = lane & 15;
  const size_t ybase = (size_t)bs * CC * HWSZ + p0 + wn * 32;
  int obase = ot * 128 + wm * 64;
#pragma unroll
  for (int mb = 0; mb < 4; ++mb) {
    int gi = mb >> 1;                        // sub-group within wave (2x32 ch)
#pragma unroll
    for (int r = 0; r < 4; ++r) {
      int o = obase + mb * 16 + orl + r;
      float pb = proj_b[o];
      unsigned short* yrow = yb + ybase + (size_t)o * HWSZ + pl;
#pragma unroll
      for (int nb = 0; nb < 2; ++nb) {
        float v = acc[mb][nb][r] + pb;
        yrow[nb * 16] = f2bf(v);
        psum[gi] += v;
        psq[gi] += v * v;
      }
    }
  }
#pragma unroll
  for (int off = 32; off > 0; off >>= 1) {
#pragma unroll
    for (int k = 0; k < 2; ++k) {
      psum[k] += __shfl_down(psum[k], off, 64);
      psq[k] += __shfl_down(psq[k], off, 64);
    }
  }
  if (lane == 0) {
#pragma unroll
    for (int k = 0; k < 2; ++k) {
      int bg = bs * 8 + ot * 4 + wm * 2 + k;
      part[(size_t)bg * 512 + pt * 4 + wn] = psum[k];
      part[65536 + (size_t)bg * 512 + pt * 4 + wn] = psq[k];
    }
  }
#undef STAGE
}

// ---------------------------------------------------------------------------
// K4.5: reduce GN partials -> stats[bg], stats[128+bg]
// ---------------------------------------------------------------------------
__global__ __launch_bounds__(256) void reduce_kernel(
    const float* __restrict__ part, float* __restrict__ stats) {
  int bg = blockIdx.x;             // 0..127 = bs*8+g
  int t = threadIdx.x;
  const float* ps = part + (size_t)bg * 512;
  const float* pq = part + 65536 + (size_t)bg * 512;
  float s = ps[t] + ps[t + 256];
  float q = pq[t] + pq[t + 256];
#pragma unroll
  for (int off = 32; off > 0; off >>= 1) {
    s += __shfl_down(s, off, 64);
    q += __shfl_down(q, off, 64);
  }
  __shared__ float ls[8];
  if ((t & 63) == 0) { ls[t >> 6] = s; ls[4 + (t >> 6)] = q; }
  __syncthreads();
  if (t == 0) stats[bg] = ls[0] + ls[1] + ls[2] + ls[3];
  if (t == 64) stats[128 + bg] = ls[4] + ls[5] + ls[6] + ls[7];
}

// ---------------------------------------------------------------------------
// K5: GroupNorm affine + exact GELU + residual. Reads bf16 y, writes fp32 out.
// ---------------------------------------------------------------------------
__global__ __launch_bounds__(256) void out_kernel(
    const float* __restrict__ x, const unsigned short* __restrict__ yb,
    const float* __restrict__ stats, const float* __restrict__ gamma,
    const float* __restrict__ beta, float* __restrict__ out) {
  int plane = blockIdx.x;
  int b = plane >> 8, c = plane & 255, g = c >> 5;
  const float inv_n = 1.0f / (32.0f * (float)HWSZ);
  float mean = stats[b * 8 + g] * inv_n;
  float var = stats[128 + b * 8 + g] * inv_n - mean * mean;
  float rstd = rsqrtf(var + EPSV);
  float scale = gamma[c] * rstd;
  float shift = beta[c] - mean * scale;

  const size_t base = (size_t)plane * HWSZ;
  for (int i = threadIdx.x; i < HWSZ / 8; i += 256) {
    uint4 yv = *(const uint4*)(yb + base + 8 * (size_t)i);
    float4 x0 = *(const float4*)(x + base + 8 * (size_t)i);
    float4 x1 = *(const float4*)(x + base + 8 * (size_t)i + 4);
    unsigned int yw[4] = {yv.x, yv.y, yv.z, yv.w};
    float r[8];
    float xr[8] = {x0.x, x0.y, x0.z, x0.w, x1.x, x1.y, x1.z, x1.w};
#pragma unroll
    for (int k = 0; k < 8; ++k) {
      unsigned int h = (yw[k >> 1] >> ((k & 1) * 16)) & 0xffffu;
      float t = bf2f(h) * scale + shift;
      float ge = 0.5f * t * (1.0f + erff(t * 0.70710678118654752f));
      r[k] = ge + xr[k];
    }
    *(float4*)(out + base + 8 * (size_t)i) = make_float4(r[0], r[1], r[2], r[3]);
    *(float4*)(out + base + 8 * (size_t)i + 4) = make_float4(r[4], r[5], r[6], r[7]);
  }
}

// ---------------------------------------------------------------------------
extern "C" void kernel_launch(void* const* d_in, const int* in_sizes, int n_in,
                              void* d_out, int out_size, void* d_ws, size_t ws_size,
                              hipStream_t stream) {
  const float* x      = (const float*)d_in[0];
  const float* fbank  = (const float*)d_in[1];   // [NF,1,7,7]
  const float* sel_w  = (const float*)d_in[2];   // [NF,C]
  const float* sel_b  = (const float*)d_in[3];   // [NF]
  const float* proj_w = (const float*)d_in[4];   // [C,C,1,1]
  const float* proj_b = (const float*)d_in[5];   // [C]
  const float* gamma  = (const float*)d_in[6];   // [C]
  const float* beta   = (const float*)d_in[7];   // [C]
  float* out = (float*)d_out;

  // ws layout: buf0 bf16 [B*C*HW] (fb -> later yb) | buf1 bf16 [B*C*HW] (fbT)
  //            | ap bf16 [65536] | pooled | combined | stats | part[131072]
  unsigned short* fb  = (unsigned short*)d_ws;
  unsigned short* yb  = fb;                      // reuse after transpose
  unsigned short* fbT = fb + (size_t)BB * CC * HWSZ;
  unsigned short* apk = fbT + (size_t)BB * CC * HWSZ;
  float* pooled   = (float*)(apk + 65536);
  float* combined = pooled + BB * CC;
  float* stats    = combined + BB * 64;
  float* part     = stats + 256;

  hipLaunchKernelGGL(pack_a_kernel, dim3(256), dim3(256), 0, stream, proj_w, apk);
  hipLaunchKernelGGL(pool_kernel, dim3(BB * CC), dim3(256), 0, stream, x, pooled);
  hipLaunchKernelGGL(selector_kernel, dim3(1), dim3(256), 0, stream,
                     pooled, sel_w, sel_b, fbank, combined);
  hipLaunchKernelGGL(dwconv_kernel, dim3(BB * CC, HH / TR), dim3(256), 0, stream,
                     x, combined, fb);
  hipLaunchKernelGGL(transpose_kernel, dim3(BB * 4 * 256), dim3(256), 0, stream,
                     fb, fbT);
  hipLaunchKernelGGL(gemm_kernel, dim3(BB * 2 * 128), dim3(512), 0, stream,
                     fbT, apk, proj_b, yb, part);
  hipLaunchKernelGGL(reduce_kernel, dim3(128), dim3(256), 0, stream, part, stats);
  hipLaunchKernelGGL(out_kernel, dim3(BB * CC), dim3(256), 0, stream,
                     x, yb, stats, gamma, beta, out);
}

// Round 11
// 454.634 us; speedup vs baseline: 1.3074x; 1.0038x over previous
//
#include <hip/hip_runtime.h>
#include <math.h>

// Problem constants
#define BB 16
#define CC 256
#define HH 128
#define WW 128
#define HWSZ 16384        // H*W
#define NF 8
#define EPSV 1e-5f

typedef __attribute__((ext_vector_type(8))) short short8;   // 8 bf16 = 4 VGPRs
typedef __attribute__((ext_vector_type(4))) float f32x4;

static __device__ __forceinline__ unsigned short f2bf(float f) {
  unsigned int u = __float_as_uint(f);
  u += 0x7fffu + ((u >> 16) & 1u);       // round-to-nearest-even
  return (unsigned short)(u >> 16);
}

static __device__ __forceinline__ float bf2f(unsigned int h) {
  return __uint_as_float(h << 16);
}

static __device__ __forceinline__ void gload_lds16(const unsigned short* g,
                                                   unsigned short* l) {
  __builtin_amdgcn_global_load_lds(
      (const __attribute__((address_space(1))) void*)(size_t)g,
      (__attribute__((address_space(3))) void*)(unsigned)(size_t)l, 16, 0, 0);
}

// ---------------------------------------------------------------------------
// K1: fused  (a) pooled[b,c] = mean over HW   (blocks 0..4095)
//            (b) pack proj_w -> bf16 A-frag order (blocks 4096..4351)
//     ap[(MB*8+kb)*512 + lane*8 + e] = w[MB*16+(lane&15)][kb*32+(lane>>4)*8+e]
// ---------------------------------------------------------------------------
__global__ __launch_bounds__(256) void pool_pack_kernel(
    const float* __restrict__ x, const float* __restrict__ pw,
    float* __restrict__ pooled, unsigned short* __restrict__ ap) {
  int blk = blockIdx.x;
  int tid = threadIdx.x;
  if (blk >= BB * CC) {            // pack_a part
    int idx = (blk - BB * CC) * 256 + tid;      // 0..65535
    int e = idx & 7;
    int lane = (idx >> 3) & 63;
    int kb = (idx >> 9) & 7;
    int mb = idx >> 12;
    int o = mb * 16 + (lane & 15);
    int c = kb * 32 + (lane >> 4) * 8 + e;
    ap[idx] = f2bf(pw[o * 256 + c]);
    return;
  }
  // pool part
  const float4* xp = (const float4*)(x + (size_t)blk * HWSZ);
  float s = 0.f;
#pragma unroll
  for (int i = 0; i < 16; ++i) {
    float4 v = xp[tid + i * 256];
    s += v.x + v.y + v.z + v.w;
  }
#pragma unroll
  for (int off = 32; off > 0; off >>= 1) s += __shfl_down(s, off, 64);
  __shared__ float ls[4];
  if ((tid & 63) == 0) ls[tid >> 6] = s;
  __syncthreads();
  if (tid == 0) pooled[blk] = (ls[0] + ls[1] + ls[2] + ls[3]) * (1.0f / 16384.0f);
}

// ---------------------------------------------------------------------------
// K2: selector: GAP -> linear -> softmax -> mix filter bank.
// ---------------------------------------------------------------------------
__global__ __launch_bounds__(256) void selector_kernel(
    const float* __restrict__ pooled, const float* __restrict__ sel_w,
    const float* __restrict__ sel_b, const float* __restrict__ fbank,
    float* __restrict__ combined) {
  int tid = threadIdx.x;
  __shared__ float lg[BB][NF];
  __shared__ float wsm[BB][NF];
  if (tid < BB * NF) {
    int b = tid >> 3, n = tid & 7;
    const float* p = pooled + b * CC;
    const float* w = sel_w + n * CC;
    float d = sel_b[n];
    for (int c = 0; c < CC; c += 4) {
      d += p[c] * w[c] + p[c + 1] * w[c + 1] + p[c + 2] * w[c + 2] + p[c + 3] * w[c + 3];
    }
    lg[b][n] = d;
  }
  __syncthreads();
  if (tid < BB) {
    int b = tid;
    float m = lg[b][0];
#pragma unroll
    for (int n = 1; n < NF; ++n) m = fmaxf(m, lg[b][n]);
    float e[NF];
    float s = 0.f;
#pragma unroll
    for (int n = 0; n < NF; ++n) { e[n] = expf(lg[b][n] - m); s += e[n]; }
    float inv = 1.0f / s;
#pragma unroll
    for (int n = 0; n < NF; ++n) wsm[b][n] = e[n] * inv;
  }
  __syncthreads();
  for (int i = tid; i < BB * 49; i += 256) {
    int b = i / 49, j = i % 49;
    float acc = 0.f;
#pragma unroll
    for (int n = 0; n < NF; ++n) acc += wsm[b][n] * fbank[n * 49 + j];
    combined[b * 64 + j] = acc;
  }
}

// ---------------------------------------------------------------------------
// K3: depthwise 7x7 conv, per-sample filter; fp32 compute, bf16 output.
// ---------------------------------------------------------------------------
#define TR 32
__global__ __launch_bounds__(256) void dwconv_kernel(
    const float* __restrict__ x, const float* __restrict__ combined,
    unsigned short* __restrict__ fbp) {
  int plane = blockIdx.x;          // b*256 + c
  int rt = blockIdx.y;             // 0..3
  int b = plane >> 8;
  int r0 = rt * TR;
  int tid = threadIdx.x;

  __shared__ float xs[TR + 6][136];

  float kf[49];
  {
    const float* cb = combined + b * 64;
#pragma unroll
    for (int i = 0; i < 49; ++i) kf[i] = cb[i];
  }

  const size_t pbase = (size_t)plane * HWSZ;
  for (int idx = tid; idx < (TR + 6) * 34; idx += 256) {
    int row = idx / 34;
    int seg = idx % 34;
    int r = r0 - 3 + row;
    int c = seg * 4 - 4;
    float4 v = make_float4(0.f, 0.f, 0.f, 0.f);
    if (r >= 0 && r < HH && c >= 0 && c < WW) {
      v = *(const float4*)(x + pbase + (size_t)r * WW + c);
    }
    *(float4*)&xs[row][seg * 4] = v;
  }
  __syncthreads();

  int cg = tid & 31;
  int rg = tid >> 5;
  float acc[4][4] = {};

#pragma unroll
  for (int ri = 0; ri < 10; ++ri) {
    int lrow = 4 * rg + ri;
    float xr[12];
#pragma unroll
    for (int s = 0; s < 3; ++s)
      *(float4*)&xr[4 * s] = *(const float4*)&xs[lrow][cg * 4 + 4 * s];
#pragma unroll
    for (int orr = 0; orr < 4; ++orr) {
      int dy = ri - orr;
      if (dy < 0 || dy > 6) continue;
#pragma unroll
      for (int oc = 0; oc < 4; ++oc) {
#pragma unroll
        for (int dx = 0; dx < 7; ++dx) {
          acc[orr][oc] += xr[oc + dx + 1] * kf[dy * 7 + dx];
        }
      }
    }
  }

#pragma unroll
  for (int orr = 0; orr < 4; ++orr) {
    ushort4 sv;
    sv.x = f2bf(acc[orr][0]);
    sv.y = f2bf(acc[orr][1]);
    sv.z = f2bf(acc[orr][2]);
    sv.w = f2bf(acc[orr][3]);
    *(ushort4*)(fbp + pbase + (size_t)(r0 + 4 * rg + orr) * WW + 4 * cg) = sv;
  }
}

// ---------------------------------------------------------------------------
// K3.5: transpose fb[b][c][p] -> fbT[b][p][c].  (proven round 5)
// ---------------------------------------------------------------------------
__global__ __launch_bounds__(256) void transpose_kernel(
    const unsigned short* __restrict__ fb, unsigned short* __restrict__ fbT) {
  int bid = blockIdx.x;            // 16 b * 4 cstripe * 256 pstripe
  int bs = bid >> 10;
  int cs = (bid >> 8) & 3;
  int ps = bid & 255;
  int t = threadIdx.x;

  __shared__ unsigned int Ts[64][33];

  int cpair = t >> 3;              // 0..31 -> c rows {2cp, 2cp+1}
  int pch = t & 7;                 // 0..7  -> p chunk of 8
  const unsigned short* s =
      fb + ((size_t)bs * CC + cs * 64 + 2 * cpair) * HWSZ + ps * 64 + pch * 8;
  uint4 A0 = *(const uint4*)s;
  uint4 A1 = *(const uint4*)(s + HWSZ);
  unsigned int wa[4] = {A0.x, A0.y, A0.z, A0.w};
  unsigned int wb[4] = {A1.x, A1.y, A1.z, A1.w};
#pragma unroll
  for (int i = 0; i < 8; ++i) {
    int p = pch * 8 + i;
    unsigned int lo = (wa[i >> 1] >> ((i & 1) * 16)) & 0xffffu;
    unsigned int hi = (wb[i >> 1] >> ((i & 1) * 16)) & 0xffffu;
    Ts[p][cpair] = lo | (hi << 16);
  }
  __syncthreads();

  size_t obase = ((size_t)bs * HWSZ + (size_t)ps * 64) * 256 + cs * 64;
#pragma unroll
  for (int r = 0; r < 2; ++r) {
    int chunk = t + 256 * r;
    int p = chunk >> 3, ch = chunk & 7;   // row p, c-chunk of 8 (4 uints)
    uint4 v;
    v.x = Ts[p][ch * 4];
    v.y = Ts[p][ch * 4 + 1];
    v.z = Ts[p][ch * 4 + 2];
    v.w = Ts[p][ch * 4 + 3];
    *(uint4*)(fbT + obase + (size_t)p * 256 + ch * 8) = v;
  }
}

// ---------------------------------------------------------------------------
// K4: 1x1 conv as bf16 MFMA GEMM — full-M block, streamed A+B, counted vmcnt:
//     Block = 256 o x 128 p, 512 thr (8 waves = 4 wm x 2 wn, each 64o x 64p).
//     B-panel read exactly ONCE from HBM (no M-split). Per K-step (32c):
//     A 16KB (2 gloads/thr) + B 8KB (1 gload/thr) via global_load_lds,
//     double-buffered, 2-ahead, s_waitcnt vmcnt(3) mid-loop (3 ops/step).
//     A is L2-resident (128 KB) -> HBM fetch ~= B once + y write.
// ---------------------------------------------------------------------------
#define SWZ(p) ((((p) >> 1) ^ ((p) >> 4)) & 3)

__global__ __launch_bounds__(512, 2) void gemm_kernel(
    const unsigned short* __restrict__ fbT, const unsigned short* __restrict__ ap,
    const float* __restrict__ proj_b, unsigned short* __restrict__ yb,
    float* __restrict__ part) {
  int bid = blockIdx.x;            // bs*128 + pt
  int bs = bid >> 7;
  int pt = bid & 127;
  int p0 = pt * 128;
  int tid = threadIdx.x;
  int lane = tid & 63;
  int wave = tid >> 6;
  int wm = wave >> 1;              // 0..3 -> o 64-block
  int wn = wave & 1;               // 0..1 -> p 64-block

  __shared__ __align__(16) unsigned short A_lds[2][8192];  // [buf] 16 KB
  __shared__ __align__(16) unsigned short B_lds[2][4096];  // [buf] 8 KB

  // --- staging sources
  // A: thread t stages MB=(t>>6) and MB=8+(t>>6); ap frag = MB*4096 + kb*512 + lane*8
  const unsigned short* asrc0 =
      ap + (size_t)(tid >> 6) * 4096 + (size_t)(tid & 63) * 8;
  unsigned short* adst = &A_lds[0][0] + (size_t)tid * 8;
  // B: fbT[bs][p0+sp][kb*32 + sj*8], sj pre-XOR'd (rule #21)
  int sp = tid >> 2;               // 0..127
  int sj = (tid & 3) ^ SWZ(sp);
  const unsigned short* bsrc0 =
      fbT + ((size_t)bs * HWSZ + p0 + sp) * 256 + sj * 8;
  unsigned short* bdst = &B_lds[0][0] + (size_t)tid * 8;

#define STAGE(kb, buf)                                                        \
  do {                                                                        \
    gload_lds16(asrc0 + (size_t)(kb) * 512, adst + (size_t)(buf) * 8192);     \
    gload_lds16(asrc0 + 32768 + (size_t)(kb) * 512,                           \
                adst + (size_t)(buf) * 8192 + 4096);                          \
    gload_lds16(bsrc0 + (size_t)(kb) * 32, bdst + (size_t)(buf) * 4096);      \
  } while (0)

  // prologue: panels 0,1 in flight (6 gloads/thread)
  STAGE(0, 0);
  STAGE(1, 1);

  f32x4 acc[4][4];
#pragma unroll
  for (int mb = 0; mb < 4; ++mb)
#pragma unroll
    for (int nb = 0; nb < 4; ++nb) acc[mb][nb] = (f32x4){0.f, 0.f, 0.f, 0.f};

  // LDS read offsets (elements)
  int aofs[4];
#pragma unroll
  for (int mb = 0; mb < 4; ++mb) aofs[mb] = ((wm * 4 + mb) * 64 + lane) * 8;
  int bofs[4];
#pragma unroll
  for (int nb = 0; nb < 4; ++nb) {
    int pp = wn * 64 + nb * 16 + (lane & 15);
    bofs[nb] = pp * 32 + (((lane >> 4) * 8) ^ (SWZ(pp) << 3));
  }

#pragma unroll
  for (int kb = 0; kb < 8; ++kb) {
    const int cur = kb & 1;
    if (kb < 7) {
      asm volatile("s_waitcnt vmcnt(3)" ::: "memory");  // step kb done; kb+1 flying
    } else {
      asm volatile("s_waitcnt vmcnt(0)" ::: "memory");
    }
    __builtin_amdgcn_s_barrier();

    short8 af[4], bfr[4];
#pragma unroll
    for (int mb = 0; mb < 4; ++mb)
      af[mb] = *(const short8*)(&A_lds[cur][0] + aofs[mb]);
#pragma unroll
    for (int nb = 0; nb < 4; ++nb)
      bfr[nb] = *(const short8*)(&B_lds[cur][0] + bofs[nb]);
    asm volatile("s_waitcnt lgkmcnt(0)" ::: "memory");
    __builtin_amdgcn_sched_barrier(0);
    __builtin_amdgcn_s_barrier();            // all waves done reading cur bufs

    if (kb < 6) STAGE(kb + 2, cur);          // refill cur; flies during MFMAs
    __builtin_amdgcn_sched_barrier(0);

#pragma unroll
    for (int mb = 0; mb < 4; ++mb)
#pragma unroll
      for (int nb = 0; nb < 4; ++nb)
        acc[mb][nb] = __builtin_amdgcn_mfma_f32_16x16x32_bf16(
            af[mb], bfr[nb], acc[mb][nb], 0, 0, 0);
  }

  // ---- epilogue: bias, y store (bf16), GN partials (no atomics)
  // C/D layout: col(p) = lane&15, row(o) = (lane>>4)*4 + reg
  float psum[2] = {0.f, 0.f}, psq[2] = {0.f, 0.f};
  int orl = (lane >> 4) * 4;
  int pl = lane & 15;
  const size_t ybase = (size_t)bs * CC * HWSZ + p0 + wn * 64;
  int obase = wm * 64;
#pragma unroll
  for (int mb = 0; mb < 4; ++mb) {
    int gi = mb >> 1;                        // wave covers 2 GN groups (64 ch)
#pragma unroll
    for (int r = 0; r < 4; ++r) {
      int o = obase + mb * 16 + orl + r;
      float pb = proj_b[o];
      unsigned short* yrow = yb + ybase + (size_t)o * HWSZ + pl;
#pragma unroll
      for (int nb = 0; nb < 4; ++nb) {
        float v = acc[mb][nb][r] + pb;
        yrow[nb * 16] = f2bf(v);
        psum[gi] += v;
        psq[gi] += v * v;
      }
    }
  }
#pragma unroll
  for (int off = 32; off > 0; off >>= 1) {
#pragma unroll
    for (int k = 0; k < 2; ++k) {
      psum[k] += __shfl_down(psum[k], off, 64);
      psq[k] += __shfl_down(psq[k], off, 64);
    }
  }
  if (lane == 0) {
#pragma unroll
    for (int k = 0; k < 2; ++k) {
      int bg = bs * 8 + wm * 2 + k;
      part[(size_t)bg * 256 + pt * 2 + wn] = psum[k];
      part[32768 + (size_t)bg * 256 + pt * 2 + wn] = psq[k];
    }
  }
#undef STAGE
}

// ---------------------------------------------------------------------------
// K4.5: reduce GN partials (256 per group) -> stats[bg], stats[128+bg]
// ---------------------------------------------------------------------------
__global__ __launch_bounds__(256) void reduce_kernel(
    const float* __restrict__ part, float* __restrict__ stats) {
  int bg = blockIdx.x;             // 0..127 = bs*8+g
  int t = threadIdx.x;
  float s = part[(size_t)bg * 256 + t];
  float q = part[32768 + (size_t)bg * 256 + t];
#pragma unroll
  for (int off = 32; off > 0; off >>= 1) {
    s += __shfl_down(s, off, 64);
    q += __shfl_down(q, off, 64);
  }
  __shared__ float ls[8];
  if ((t & 63) == 0) { ls[t >> 6] = s; ls[4 + (t >> 6)] = q; }
  __syncthreads();
  if (t == 0) stats[bg] = ls[0] + ls[1] + ls[2] + ls[3];
  if (t == 64) stats[128 + bg] = ls[4] + ls[5] + ls[6] + ls[7];
}

// ---------------------------------------------------------------------------
// K5: GroupNorm affine + exact GELU + residual. Reads bf16 y, writes fp32 out.
// ---------------------------------------------------------------------------
__global__ __launch_bounds__(256) void out_kernel(
    const float* __restrict__ x, const unsigned short* __restrict__ yb,
    const float* __restrict__ stats, const float* __restrict__ gamma,
    const float* __restrict__ beta, float* __restrict__ out) {
  int plane = blockIdx.x;
  int b = plane >> 8, c = plane & 255, g = c >> 5;
  const float inv_n = 1.0f / (32.0f * (float)HWSZ);
  float mean = stats[b * 8 + g] * inv_n;
  float var = stats[128 + b * 8 + g] * inv_n - mean * mean;
  float rstd = rsqrtf(var + EPSV);
  float scale = gamma[c] * rstd;
  float shift = beta[c] - mean * scale;

  const size_t base = (size_t)plane * HWSZ;
  for (int i = threadIdx.x; i < HWSZ / 8; i += 256) {
    uint4 yv = *(const uint4*)(yb + base + 8 * (size_t)i);
    float4 x0 = *(const float4*)(x + base + 8 * (size_t)i);
    float4 x1 = *(const float4*)(x + base + 8 * (size_t)i + 4);
    unsigned int yw[4] = {yv.x, yv.y, yv.z, yv.w};
    float r[8];
    float xr[8] = {x0.x, x0.y, x0.z, x0.w, x1.x, x1.y, x1.z, x1.w};
#pragma unroll
    for (int k = 0; k < 8; ++k) {
      unsigned int h = (yw[k >> 1] >> ((k & 1) * 16)) & 0xffffu;
      float t = bf2f(h) * scale + shift;
      float ge = 0.5f * t * (1.0f + erff(t * 0.70710678118654752f));
      r[k] = ge + xr[k];
    }
    *(float4*)(out + base + 8 * (size_t)i) = make_float4(r[0], r[1], r[2], r[3]);
    *(float4*)(out + base + 8 * (size_t)i + 4) = make_float4(r[4], r[5], r[6], r[7]);
  }
}

// ---------------------------------------------------------------------------
extern "C" void kernel_launch(void* const* d_in, const int* in_sizes, int n_in,
                              void* d_out, int out_size, void* d_ws, size_t ws_size,
                              hipStream_t stream) {
  const float* x      = (const float*)d_in[0];
  const float* fbank  = (const float*)d_in[1];   // [NF,1,7,7]
  const float* sel_w  = (const float*)d_in[2];   // [NF,C]
  const float* sel_b  = (const float*)d_in[3];   // [NF]
  const float* proj_w = (const float*)d_in[4];   // [C,C,1,1]
  const float* proj_b = (const float*)d_in[5];   // [C]
  const float* gamma  = (const float*)d_in[6];   // [C]
  const float* beta   = (const float*)d_in[7];   // [C]
  float* out = (float*)d_out;

  // ws layout: buf0 bf16 [B*C*HW] (fb -> later yb) | buf1 bf16 [B*C*HW] (fbT)
  //            | ap bf16 [65536] | pooled | combined | stats | part[65536]
  unsigned short* fb  = (unsigned short*)d_ws;
  unsigned short* yb  = fb;                      // reuse after transpose
  unsigned short* fbT = fb + (size_t)BB * CC * HWSZ;
  unsigned short* apk = fbT + (size_t)BB * CC * HWSZ;
  float* pooled   = (float*)(apk + 65536);
  float* combined = pooled + BB * CC;
  float* stats    = combined + BB * 64;
  float* part     = stats + 256;

  hipLaunchKernelGGL(pool_pack_kernel, dim3(BB * CC + 256), dim3(256), 0, stream,
                     x, proj_w, pooled, apk);
  hipLaunchKernelGGL(selector_kernel, dim3(1), dim3(256), 0, stream,
                     pooled, sel_w, sel_b, fbank, combined);
  hipLaunchKernelGGL(dwconv_kernel, dim3(BB * CC, HH / TR), dim3(256), 0, stream,
                     x, combined, fb);
  hipLaunchKernelGGL(transpose_kernel, dim3(BB * 4 * 256), dim3(256), 0, stream,
                     fb, fbT);
  hipLaunchKernelGGL(gemm_kernel, dim3(BB * 128), dim3(512), 0, stream,
                     fbT, apk, proj_b, yb, part);
  hipLaunchKernelGGL(reduce_kernel, dim3(128), dim3(256), 0, stream, part, stats);
  hipLaunchKernelGGL(out_kernel, dim3(BB * CC), dim3(256), 0, stream,
                     x, yb, stats, gamma, beta, out);
}

// Round 12
// 428.014 us; speedup vs baseline: 1.3887x; 1.0622x over previous
//
#include <hip/hip_runtime.h>
#include <math.h>

// Problem constants
#define BB 16
#define CC 256
#define HH 128
#define WW 128
#define HWSZ 16384        // H*W
#define NF 8
#define EPSV 1e-5f

typedef __attribute__((ext_vector_type(8))) short short8;   // 8 bf16 = 4 VGPRs
typedef __attribute__((ext_vector_type(4))) float f32x4;

static __device__ __forceinline__ unsigned short f2bf(float f) {
  unsigned int u = __float_as_uint(f);
  u += 0x7fffu + ((u >> 16) & 1u);       // round-to-nearest-even
  return (unsigned short)(u >> 16);
}

static __device__ __forceinline__ float bf2f(unsigned int h) {
  return __uint_as_float(h << 16);
}

static __device__ __forceinline__ void gload_lds16(const unsigned short* g,
                                                   unsigned short* l) {
  __builtin_amdgcn_global_load_lds(
      (const __attribute__((address_space(1))) void*)(size_t)g,
      (__attribute__((address_space(3))) void*)(unsigned)(size_t)l, 16, 0, 0);
}

// ---------------------------------------------------------------------------
// K1: fused  (a) pooled[b,c] = mean over HW   (blocks 0..4095)
//            (b) pack proj_w -> bf16 A-frag order (blocks 4096..4351)
// ---------------------------------------------------------------------------
__global__ __launch_bounds__(256) void pool_pack_kernel(
    const float* __restrict__ x, const float* __restrict__ pw,
    float* __restrict__ pooled, unsigned short* __restrict__ ap) {
  int blk = blockIdx.x;
  int tid = threadIdx.x;
  if (blk >= BB * CC) {            // pack_a part
    int idx = (blk - BB * CC) * 256 + tid;      // 0..65535
    int e = idx & 7;
    int lane = (idx >> 3) & 63;
    int kb = (idx >> 9) & 7;
    int mb = idx >> 12;
    int o = mb * 16 + (lane & 15);
    int c = kb * 32 + (lane >> 4) * 8 + e;
    ap[idx] = f2bf(pw[o * 256 + c]);
    return;
  }
  // pool part
  const float4* xp = (const float4*)(x + (size_t)blk * HWSZ);
  float s = 0.f;
#pragma unroll
  for (int i = 0; i < 16; ++i) {
    float4 v = xp[tid + i * 256];
    s += v.x + v.y + v.z + v.w;
  }
#pragma unroll
  for (int off = 32; off > 0; off >>= 1) s += __shfl_down(s, off, 64);
  __shared__ float ls[4];
  if ((tid & 63) == 0) ls[tid >> 6] = s;
  __syncthreads();
  if (tid == 0) pooled[blk] = (ls[0] + ls[1] + ls[2] + ls[3]) * (1.0f / 16384.0f);
}

// ---------------------------------------------------------------------------
// K2: selector: GAP -> linear -> softmax -> mix filter bank.
// ---------------------------------------------------------------------------
__global__ __launch_bounds__(256) void selector_kernel(
    const float* __restrict__ pooled, const float* __restrict__ sel_w,
    const float* __restrict__ sel_b, const float* __restrict__ fbank,
    float* __restrict__ combined) {
  int tid = threadIdx.x;
  __shared__ float lg[BB][NF];
  __shared__ float wsm[BB][NF];
  if (tid < BB * NF) {
    int b = tid >> 3, n = tid & 7;
    const float* p = pooled + b * CC;
    const float* w = sel_w + n * CC;
    float d = sel_b[n];
    for (int c = 0; c < CC; c += 4) {
      d += p[c] * w[c] + p[c + 1] * w[c + 1] + p[c + 2] * w[c + 2] + p[c + 3] * w[c + 3];
    }
    lg[b][n] = d;
  }
  __syncthreads();
  if (tid < BB) {
    int b = tid;
    float m = lg[b][0];
#pragma unroll
    for (int n = 1; n < NF; ++n) m = fmaxf(m, lg[b][n]);
    float e[NF];
    float s = 0.f;
#pragma unroll
    for (int n = 0; n < NF; ++n) { e[n] = expf(lg[b][n] - m); s += e[n]; }
    float inv = 1.0f / s;
#pragma unroll
    for (int n = 0; n < NF; ++n) wsm[b][n] = e[n] * inv;
  }
  __syncthreads();
  for (int i = tid; i < BB * 49; i += 256) {
    int b = i / 49, j = i % 49;
    float acc = 0.f;
#pragma unroll
    for (int n = 0; n < NF; ++n) acc += wsm[b][n] * fbank[n * 49 + j];
    combined[b * 64 + j] = acc;
  }
}

// ---------------------------------------------------------------------------
// K3: depthwise 7x7 conv, per-sample filter; fp32 compute, bf16 output.
// ---------------------------------------------------------------------------
#define TR 32
__global__ __launch_bounds__(256) void dwconv_kernel(
    const float* __restrict__ x, const float* __restrict__ combined,
    unsigned short* __restrict__ fbp) {
  int plane = blockIdx.x;          // b*256 + c
  int rt = blockIdx.y;             // 0..3
  int b = plane >> 8;
  int r0 = rt * TR;
  int tid = threadIdx.x;

  __shared__ float xs[TR + 6][136];

  float kf[49];
  {
    const float* cb = combined + b * 64;
#pragma unroll
    for (int i = 0; i < 49; ++i) kf[i] = cb[i];
  }

  const size_t pbase = (size_t)plane * HWSZ;
  for (int idx = tid; idx < (TR + 6) * 34; idx += 256) {
    int row = idx / 34;
    int seg = idx % 34;
    int r = r0 - 3 + row;
    int c = seg * 4 - 4;
    float4 v = make_float4(0.f, 0.f, 0.f, 0.f);
    if (r >= 0 && r < HH && c >= 0 && c < WW) {
      v = *(const float4*)(x + pbase + (size_t)r * WW + c);
    }
    *(float4*)&xs[row][seg * 4] = v;
  }
  __syncthreads();

  int cg = tid & 31;
  int rg = tid >> 5;
  float acc[4][4] = {};

#pragma unroll
  for (int ri = 0; ri < 10; ++ri) {
    int lrow = 4 * rg + ri;
    float xr[12];
#pragma unroll
    for (int s = 0; s < 3; ++s)
      *(float4*)&xr[4 * s] = *(const float4*)&xs[lrow][cg * 4 + 4 * s];
#pragma unroll
    for (int orr = 0; orr < 4; ++orr) {
      int dy = ri - orr;
      if (dy < 0 || dy > 6) continue;
#pragma unroll
      for (int oc = 0; oc < 4; ++oc) {
#pragma unroll
        for (int dx = 0; dx < 7; ++dx) {
          acc[orr][oc] += xr[oc + dx + 1] * kf[dy * 7 + dx];
        }
      }
    }
  }

#pragma unroll
  for (int orr = 0; orr < 4; ++orr) {
    ushort4 sv;
    sv.x = f2bf(acc[orr][0]);
    sv.y = f2bf(acc[orr][1]);
    sv.z = f2bf(acc[orr][2]);
    sv.w = f2bf(acc[orr][3]);
    *(ushort4*)(fbp + pbase + (size_t)(r0 + 4 * rg + orr) * WW + 4 * cg) = sv;
  }
}

// ---------------------------------------------------------------------------
// K4: 1x1 conv as bf16 MFMA GEMM — NO separate transpose: B repacked in-kernel.
//     Block = 256 o x 128 p, 512 thr (8 waves = 4 wm x 2 wn, each 64o x 64p).
//     Per K-step (32c): A 16KB via global_load_lds (2/thr), B reg-loaded
//     c-major from fb (2x dwordx2/thr, depth-2) then swizzle-packed into LDS
//     [128p][32c-swz] via 4x ds_write_b32 (r4-proven mapping). Counted
//     vmcnt(4) mid-loop (4 vm ops/iter). 2 barriers/iter. GN partials global.
// ---------------------------------------------------------------------------
#define SWZ(p) ((((p) >> 1) ^ ((p) >> 4)) & 3)

__global__ __launch_bounds__(512, 2) void gemm_kernel(
    const unsigned short* __restrict__ fb, const unsigned short* __restrict__ ap,
    const float* __restrict__ proj_b, unsigned short* __restrict__ yb,
    float* __restrict__ part) {
  int bid = blockIdx.x;            // bs*128 + pt
  int bs = bid >> 7;
  int pt = bid & 127;
  int p0 = pt * 128;
  int tid = threadIdx.x;
  int lane = tid & 63;
  int wave = tid >> 6;
  int wm = wave >> 1;              // 0..3 -> o 64-block
  int wn = wave & 1;               // 0..1 -> p 64-block

  __shared__ __align__(16) unsigned short A_lds[2][8192];  // 2 x 16 KB
  __shared__ __align__(16) unsigned short B_lds[2][4096];  // 2 x 8 KB

  // --- A staging: thread t stages MB=(t>>6) and MB=8+(t>>6)
  const unsigned short* asrc0 =
      ap + (size_t)(tid >> 6) * 4096 + (size_t)(tid & 63) * 8;
  unsigned short* adst = &A_lds[0][0] + (size_t)tid * 8;

  // --- B staging: thread t reg-loads c rows {2cp,2cp+1}, p = 4pq..4pq+3
  int cp = tid >> 5;               // 0..15
  int pq = tid & 31;               // 0..31
  const unsigned short* bsrc0 =
      fb + ((size_t)bs * CC + 2 * cp) * HWSZ + p0 + 4 * pq;

  uint2 bregs[2][2];               // [slot][row], slot = panel parity

#define STAGE_A(kb, buf)                                                      \
  do {                                                                        \
    gload_lds16(asrc0 + (size_t)(kb) * 512, adst + (size_t)(buf) * 8192);     \
    gload_lds16(asrc0 + 32768 + (size_t)(kb) * 512,                           \
                adst + (size_t)(buf) * 8192 + 4096);                          \
  } while (0)
#define LOAD_B(kb, slot)                                                      \
  do {                                                                        \
    const unsigned short* s_ = bsrc0 + (size_t)(kb) * 32 * HWSZ;              \
    bregs[slot][0] = *(const uint2*)s_;                                       \
    bregs[slot][1] = *(const uint2*)(s_ + HWSZ);                              \
  } while (0)
#define WRITE_B(slot, buf)                                                    \
  do {                                                                        \
    unsigned int w0_[2] = {bregs[slot][0].x, bregs[slot][0].y};               \
    unsigned int w1_[2] = {bregs[slot][1].x, bregs[slot][1].y};               \
    _Pragma("unroll")                                                         \
    for (int j_ = 0; j_ < 4; ++j_) {                                          \
      int p_ = 4 * pq + j_;                                                   \
      int cc_ = (2 * cp) ^ (SWZ(p_) << 3);                                    \
      unsigned int lo_ = (w0_[j_ >> 1] >> ((j_ & 1) * 16)) & 0xffffu;         \
      unsigned int hi_ = (w1_[j_ >> 1] >> ((j_ & 1) * 16)) & 0xffffu;         \
      *(unsigned int*)&B_lds[buf][p_ * 32 + cc_] = lo_ | (hi_ << 16);         \
    }                                                                         \
  } while (0)

  // ---- prologue: A(0),B(0),A(1),B(1) in flight (8 vm ops)
  STAGE_A(0, 0);
  LOAD_B(0, 0);
  STAGE_A(1, 1);
  LOAD_B(1, 1);

  f32x4 acc[4][4];
#pragma unroll
  for (int mb = 0; mb < 4; ++mb)
#pragma unroll
    for (int nb = 0; nb < 4; ++nb) acc[mb][nb] = (f32x4){0.f, 0.f, 0.f, 0.f};

  // LDS read offsets (elements)
  int aofs[4];
#pragma unroll
  for (int mb = 0; mb < 4; ++mb) aofs[mb] = ((wm * 4 + mb) * 64 + lane) * 8;
  int bofs[4];
#pragma unroll
  for (int nb = 0; nb < 4; ++nb) {
    int pp = wn * 64 + nb * 16 + (lane & 15);
    bofs[nb] = pp * 32 + (((lane >> 4) * 8) ^ (SWZ(pp) << 3));
  }

  // drain A(0)+B(0) (first 4 of 8), publish B(0)
  asm volatile("s_waitcnt vmcnt(4)" ::: "memory");
  WRITE_B(0, 0);
  asm volatile("s_waitcnt lgkmcnt(0)" ::: "memory");
  __builtin_amdgcn_s_barrier();

#pragma unroll
  for (int kb = 0; kb < 8; ++kb) {
    const int cur = kb & 1;
    // ---- read fragments of panel kb
    short8 af[4], bfr[4];
#pragma unroll
    for (int mb = 0; mb < 4; ++mb)
      af[mb] = *(const short8*)(&A_lds[cur][0] + aofs[mb]);
#pragma unroll
    for (int nb = 0; nb < 4; ++nb)
      bfr[nb] = *(const short8*)(&B_lds[cur][0] + bofs[nb]);
    asm volatile("s_waitcnt lgkmcnt(0)" ::: "memory");
    __builtin_amdgcn_sched_barrier(0);
    __builtin_amdgcn_s_barrier();            // all waves done reading cur bufs

    if (kb < 6) {                            // issue panel kb+2 (4 vm ops)
      STAGE_A(kb + 2, cur);
      LOAD_B(kb + 2, cur);                   // into slot cur
      __builtin_amdgcn_sched_barrier(0);
    }
    if (kb < 6) {
      asm volatile("s_waitcnt vmcnt(4)" ::: "memory");   // A,B(kb+1) arrived
    } else if (kb == 6) {
      asm volatile("s_waitcnt vmcnt(0)" ::: "memory");   // nothing issued; drain
    }
    if (kb < 7) {
      WRITE_B(cur ^ 1, cur ^ 1);             // publish B(kb+1) (slot/buf = cur^1)
      asm volatile("s_waitcnt lgkmcnt(0)" ::: "memory");
      __builtin_amdgcn_s_barrier();          // panel kb+1 ready for all waves
    }

#pragma unroll
    for (int mb = 0; mb < 4; ++mb)
#pragma unroll
      for (int nb = 0; nb < 4; ++nb)
        acc[mb][nb] = __builtin_amdgcn_mfma_f32_16x16x32_bf16(
            af[mb], bfr[nb], acc[mb][nb], 0, 0, 0);
  }

  // ---- epilogue: bias, y store (bf16), GN partials (no atomics)
  // C/D layout: col(p) = lane&15, row(o) = (lane>>4)*4 + reg
  float psum[2] = {0.f, 0.f}, psq[2] = {0.f, 0.f};
  int orl = (lane >> 4) * 4;
  int pl = lane & 15;
  const size_t ybase = (size_t)bs * CC * HWSZ + p0 + wn * 64;
  int obase = wm * 64;
#pragma unroll
  for (int mb = 0; mb < 4; ++mb) {
    int gi = mb >> 1;                        // wave covers 2 GN groups (64 ch)
#pragma unroll
    for (int r = 0; r < 4; ++r) {
      int o = obase + mb * 16 + orl + r;
      float pb = proj_b[o];
      unsigned short* yrow = yb + ybase + (size_t)o * HWSZ + pl;
#pragma unroll
      for (int nb = 0; nb < 4; ++nb) {
        float v = acc[mb][nb][r] + pb;
        yrow[nb * 16] = f2bf(v);
        psum[gi] += v;
        psq[gi] += v * v;
      }
    }
  }
#pragma unroll
  for (int off = 32; off > 0; off >>= 1) {
#pragma unroll
    for (int k = 0; k < 2; ++k) {
      psum[k] += __shfl_down(psum[k], off, 64);
      psq[k] += __shfl_down(psq[k], off, 64);
    }
  }
  if (lane == 0) {
#pragma unroll
    for (int k = 0; k < 2; ++k) {
      int bg = bs * 8 + wm * 2 + k;
      part[(size_t)bg * 256 + pt * 2 + wn] = psum[k];
      part[32768 + (size_t)bg * 256 + pt * 2 + wn] = psq[k];
    }
  }
#undef STAGE_A
#undef LOAD_B
#undef WRITE_B
}

// ---------------------------------------------------------------------------
// K4.5: reduce GN partials (256 per group) -> stats[bg], stats[128+bg]
// ---------------------------------------------------------------------------
__global__ __launch_bounds__(256) void reduce_kernel(
    const float* __restrict__ part, float* __restrict__ stats) {
  int bg = blockIdx.x;             // 0..127 = bs*8+g
  int t = threadIdx.x;
  float s = part[(size_t)bg * 256 + t];
  float q = part[32768 + (size_t)bg * 256 + t];
#pragma unroll
  for (int off = 32; off > 0; off >>= 1) {
    s += __shfl_down(s, off, 64);
    q += __shfl_down(q, off, 64);
  }
  __shared__ float ls[8];
  if ((t & 63) == 0) { ls[t >> 6] = s; ls[4 + (t >> 6)] = q; }
  __syncthreads();
  if (t == 0) stats[bg] = ls[0] + ls[1] + ls[2] + ls[3];
  if (t == 64) stats[128 + bg] = ls[4] + ls[5] + ls[6] + ls[7];
}

// ---------------------------------------------------------------------------
// K5: GroupNorm affine + exact GELU + residual. Reads bf16 y, writes fp32 out.
// ---------------------------------------------------------------------------
__global__ __launch_bounds__(256) void out_kernel(
    const float* __restrict__ x, const unsigned short* __restrict__ yb,
    const float* __restrict__ stats, const float* __restrict__ gamma,
    const float* __restrict__ beta, float* __restrict__ out) {
  int plane = blockIdx.x;
  int b = plane >> 8, c = plane & 255, g = c >> 5;
  const float inv_n = 1.0f / (32.0f * (float)HWSZ);
  float mean = stats[b * 8 + g] * inv_n;
  float var = stats[128 + b * 8 + g] * inv_n - mean * mean;
  float rstd = rsqrtf(var + EPSV);
  float scale = gamma[c] * rstd;
  float shift = beta[c] - mean * scale;

  const size_t base = (size_t)plane * HWSZ;
  for (int i = threadIdx.x; i < HWSZ / 8; i += 256) {
    uint4 yv = *(const uint4*)(yb + base + 8 * (size_t)i);
    float4 x0 = *(const float4*)(x + base + 8 * (size_t)i);
    float4 x1 = *(const float4*)(x + base + 8 * (size_t)i + 4);
    unsigned int yw[4] = {yv.x, yv.y, yv.z, yv.w};
    float r[8];
    float xr[8] = {x0.x, x0.y, x0.z, x0.w, x1.x, x1.y, x1.z, x1.w};
#pragma unroll
    for (int k = 0; k < 8; ++k) {
      unsigned int h = (yw[k >> 1] >> ((k & 1) * 16)) & 0xffffu;
      float t = bf2f(h) * scale + shift;
      float ge = 0.5f * t * (1.0f + erff(t * 0.70710678118654752f));
      r[k] = ge + xr[k];
    }
    *(float4*)(out + base + 8 * (size_t)i) = make_float4(r[0], r[1], r[2], r[3]);
    *(float4*)(out + base + 8 * (size_t)i + 4) = make_float4(r[4], r[5], r[6], r[7]);
  }
}

// ---------------------------------------------------------------------------
extern "C" void kernel_launch(void* const* d_in, const int* in_sizes, int n_in,
                              void* d_out, int out_size, void* d_ws, size_t ws_size,
                              hipStream_t stream) {
  const float* x      = (const float*)d_in[0];
  const float* fbank  = (const float*)d_in[1];   // [NF,1,7,7]
  const float* sel_w  = (const float*)d_in[2];   // [NF,C]
  const float* sel_b  = (const float*)d_in[3];   // [NF]
  const float* proj_w = (const float*)d_in[4];   // [C,C,1,1]
  const float* proj_b = (const float*)d_in[5];   // [C]
  const float* gamma  = (const float*)d_in[6];   // [C]
  const float* beta   = (const float*)d_in[7];   // [C]
  float* out = (float*)d_out;

  // ws layout: fb bf16 [B*C*HW] | yb bf16 [B*C*HW] (distinct: gemm reads fb!)
  //            | ap bf16 [65536] | pooled | combined | stats | part[65536]
  unsigned short* fb  = (unsigned short*)d_ws;
  unsigned short* yb  = fb + (size_t)BB * CC * HWSZ;
  unsigned short* apk = yb + (size_t)BB * CC * HWSZ;
  float* pooled   = (float*)(apk + 65536);
  float* combined = pooled + BB * CC;
  float* stats    = combined + BB * 64;
  float* part     = stats + 256;

  hipLaunchKernelGGL(pool_pack_kernel, dim3(BB * CC + 256), dim3(256), 0, stream,
                     x, proj_w, pooled, apk);
  hipLaunchKernelGGL(selector_kernel, dim3(1), dim3(256), 0, stream,
                     pooled, sel_w, sel_b, fbank, combined);
  hipLaunchKernelGGL(dwconv_kernel, dim3(BB * CC, HH / TR), dim3(256), 0, stream,
                     x, combined, fb);
  hipLaunchKernelGGL(gemm_kernel, dim3(BB * 128), dim3(512), 0, stream,
                     fb, apk, proj_b, yb, part);
  hipLaunchKernelGGL(reduce_kernel, dim3(128), dim3(256), 0, stream, part, stats);
  hipLaunchKernelGGL(out_kernel, dim3(BB * CC), dim3(256), 0, stream,
                     x, yb, stats, gamma, beta, out);
}

// Round 13
// 420.549 us; speedup vs baseline: 1.4133x; 1.0177x over previous
//
#include <hip/hip_runtime.h>
#include <math.h>

// Problem constants
#define BB 16
#define CC 256
#define HH 128
#define WW 128
#define HWSZ 16384        // H*W
#define NF 8
#define EPSV 1e-5f

typedef __attribute__((ext_vector_type(8))) short short8;   // 8 bf16 = 4 VGPRs
typedef __attribute__((ext_vector_type(4))) float f32x4;

static __device__ __forceinline__ unsigned short f2bf(float f) {
  unsigned int u = __float_as_uint(f);
  u += 0x7fffu + ((u >> 16) & 1u);       // round-to-nearest-even
  return (unsigned short)(u >> 16);
}

static __device__ __forceinline__ float bf2f(unsigned int h) {
  return __uint_as_float(h << 16);
}

static __device__ __forceinline__ void gload_lds16(const unsigned short* g,
                                                   unsigned short* l) {
  __builtin_amdgcn_global_load_lds(
      (const __attribute__((address_space(1))) void*)(size_t)g,
      (__attribute__((address_space(3))) void*)(unsigned)(size_t)l, 16, 0, 0);
}

// ---------------------------------------------------------------------------
// K1: fused  (a) pooled[b,c] = mean over HW   (blocks 0..4095)
//            (b) pack proj_w -> bf16 A-frag order (blocks 4096..4351)
// ---------------------------------------------------------------------------
__global__ __launch_bounds__(256) void pool_pack_kernel(
    const float* __restrict__ x, const float* __restrict__ pw,
    float* __restrict__ pooled, unsigned short* __restrict__ ap) {
  int blk = blockIdx.x;
  int tid = threadIdx.x;
  if (blk >= BB * CC) {            // pack_a part
    int idx = (blk - BB * CC) * 256 + tid;      // 0..65535
    int e = idx & 7;
    int lane = (idx >> 3) & 63;
    int kb = (idx >> 9) & 7;
    int mb = idx >> 12;
    int o = mb * 16 + (lane & 15);
    int c = kb * 32 + (lane >> 4) * 8 + e;
    ap[idx] = f2bf(pw[o * 256 + c]);
    return;
  }
  // pool part
  const float4* xp = (const float4*)(x + (size_t)blk * HWSZ);
  float s = 0.f;
#pragma unroll
  for (int i = 0; i < 16; ++i) {
    float4 v = xp[tid + i * 256];
    s += v.x + v.y + v.z + v.w;
  }
#pragma unroll
  for (int off = 32; off > 0; off >>= 1) s += __shfl_down(s, off, 64);
  __shared__ float ls[4];
  if ((tid & 63) == 0) ls[tid >> 6] = s;
  __syncthreads();
  if (tid == 0) pooled[blk] = (ls[0] + ls[1] + ls[2] + ls[3]) * (1.0f / 16384.0f);
}

// ---------------------------------------------------------------------------
// K2: selector: GAP -> linear -> softmax -> mix filter bank.
// ---------------------------------------------------------------------------
__global__ __launch_bounds__(256) void selector_kernel(
    const float* __restrict__ pooled, const float* __restrict__ sel_w,
    const float* __restrict__ sel_b, const float* __restrict__ fbank,
    float* __restrict__ combined) {
  int tid = threadIdx.x;
  __shared__ float lg[BB][NF];
  __shared__ float wsm[BB][NF];
  if (tid < BB * NF) {
    int b = tid >> 3, n = tid & 7;
    const float* p = pooled + b * CC;
    const float* w = sel_w + n * CC;
    float d = sel_b[n];
    for (int c = 0; c < CC; c += 4) {
      d += p[c] * w[c] + p[c + 1] * w[c + 1] + p[c + 2] * w[c + 2] + p[c + 3] * w[c + 3];
    }
    lg[b][n] = d;
  }
  __syncthreads();
  if (tid < BB) {
    int b = tid;
    float m = lg[b][0];
#pragma unroll
    for (int n = 1; n < NF; ++n) m = fmaxf(m, lg[b][n]);
    float e[NF];
    float s = 0.f;
#pragma unroll
    for (int n = 0; n < NF; ++n) { e[n] = expf(lg[b][n] - m); s += e[n]; }
    float inv = 1.0f / s;
#pragma unroll
    for (int n = 0; n < NF; ++n) wsm[b][n] = e[n] * inv;
  }
  __syncthreads();
  for (int i = tid; i < BB * 49; i += 256) {
    int b = i / 49, j = i % 49;
    float acc = 0.f;
#pragma unroll
    for (int n = 0; n < NF; ++n) acc += wsm[b][n] * fbank[n * 49 + j];
    combined[b * 64 + j] = acc;
  }
}

// ---------------------------------------------------------------------------
// K3: depthwise 7x7 conv, per-sample filter; fp32 compute, bf16 output.
// ---------------------------------------------------------------------------
#define TR 32
__global__ __launch_bounds__(256) void dwconv_kernel(
    const float* __restrict__ x, const float* __restrict__ combined,
    unsigned short* __restrict__ fbp) {
  int plane = blockIdx.x;          // b*256 + c
  int rt = blockIdx.y;             // 0..3
  int b = plane >> 8;
  int r0 = rt * TR;
  int tid = threadIdx.x;

  __shared__ float xs[TR + 6][136];

  float kf[49];
  {
    const float* cb = combined + b * 64;
#pragma unroll
    for (int i = 0; i < 49; ++i) kf[i] = cb[i];
  }

  const size_t pbase = (size_t)plane * HWSZ;
  for (int idx = tid; idx < (TR + 6) * 34; idx += 256) {
    int row = idx / 34;
    int seg = idx % 34;
    int r = r0 - 3 + row;
    int c = seg * 4 - 4;
    float4 v = make_float4(0.f, 0.f, 0.f, 0.f);
    if (r >= 0 && r < HH && c >= 0 && c < WW) {
      v = *(const float4*)(x + pbase + (size_t)r * WW + c);
    }
    *(float4*)&xs[row][seg * 4] = v;
  }
  __syncthreads();

  int cg = tid & 31;
  int rg = tid >> 5;
  float acc[4][4] = {};

#pragma unroll
  for (int ri = 0; ri < 10; ++ri) {
    int lrow = 4 * rg + ri;
    float xr[12];
#pragma unroll
    for (int s = 0; s < 3; ++s)
      *(float4*)&xr[4 * s] = *(const float4*)&xs[lrow][cg * 4 + 4 * s];
#pragma unroll
    for (int orr = 0; orr < 4; ++orr) {
      int dy = ri - orr;
      if (dy < 0 || dy > 6) continue;
#pragma unroll
      for (int oc = 0; oc < 4; ++oc) {
#pragma unroll
        for (int dx = 0; dx < 7; ++dx) {
          acc[orr][oc] += xr[oc + dx + 1] * kf[dy * 7 + dx];
        }
      }
    }
  }

#pragma unroll
  for (int orr = 0; orr < 4; ++orr) {
    ushort4 sv;
    sv.x = f2bf(acc[orr][0]);
    sv.y = f2bf(acc[orr][1]);
    sv.z = f2bf(acc[orr][2]);
    sv.w = f2bf(acc[orr][3]);
    *(ushort4*)(fbp + pbase + (size_t)(r0 + 4 * rg + orr) * WW + 4 * cg) = sv;
  }
}

// ---------------------------------------------------------------------------
// K4: 1x1 conv as bf16 MFMA GEMM — in-kernel B repack, 3-buffer pipeline,
//     ONE barrier per K-step.
//     Block = 256 o x 128 p, 512 thr (8 waves = 4 wm x 2 wn, each 64o x 64p).
//     Buffers rotate mod 3; panel kb+1's write-buffer was released at the
//     barrier of iter kb-2, so no read-release barrier is needed.
//     Per iter: issue loads(kb+2) -> ds_read frags(kb) -> vmcnt(4) ->
//     ds_write B(kb+1) -> lgkmcnt(0) -> MFMA -> barrier (publish kb+1).
// ---------------------------------------------------------------------------
#define SWZ(p) ((((p) >> 1) ^ ((p) >> 4)) & 3)

__global__ __launch_bounds__(512, 2) void gemm_kernel(
    const unsigned short* __restrict__ fb, const unsigned short* __restrict__ ap,
    const float* __restrict__ proj_b, unsigned short* __restrict__ yb,
    float* __restrict__ part) {
  int bid = blockIdx.x;            // bs*128 + pt
  int bs = bid >> 7;
  int pt = bid & 127;
  int p0 = pt * 128;
  int tid = threadIdx.x;
  int lane = tid & 63;
  int wave = tid >> 6;
  int wm = wave >> 1;              // 0..3 -> o 64-block
  int wn = wave & 1;               // 0..1 -> p 64-block

  __shared__ __align__(16) unsigned short A_lds[3][8192];  // 3 x 16 KB
  __shared__ __align__(16) unsigned short B_lds[3][4096];  // 3 x 8 KB

  // --- A staging: thread t stages MB=(t>>6) and MB=8+(t>>6)
  const unsigned short* asrc0 =
      ap + (size_t)(tid >> 6) * 4096 + (size_t)(tid & 63) * 8;
  unsigned short* adst = &A_lds[0][0] + (size_t)tid * 8;

  // --- B staging: thread t reg-loads c rows {2cp,2cp+1}, p = 4pq..4pq+3
  int cp = tid >> 5;               // 0..15
  int pq = tid & 31;               // 0..31
  const unsigned short* bsrc0 =
      fb + ((size_t)bs * CC + 2 * cp) * HWSZ + p0 + 4 * pq;

  uint2 bregs[3][2];               // [slot = kb%3][row]

#define STAGE_A(kb, buf)                                                      \
  do {                                                                        \
    gload_lds16(asrc0 + (size_t)(kb) * 512, adst + (size_t)(buf) * 8192);     \
    gload_lds16(asrc0 + 32768 + (size_t)(kb) * 512,                           \
                adst + (size_t)(buf) * 8192 + 4096);                          \
  } while (0)
#define LOAD_B(kb, slot)                                                      \
  do {                                                                        \
    const unsigned short* s_ = bsrc0 + (size_t)(kb) * 32 * HWSZ;              \
    bregs[slot][0] = *(const uint2*)s_;                                       \
    bregs[slot][1] = *(const uint2*)(s_ + HWSZ);                              \
  } while (0)
#define WRITE_B(slot, buf)                                                    \
  do {                                                                        \
    unsigned int w0_[2] = {bregs[slot][0].x, bregs[slot][0].y};               \
    unsigned int w1_[2] = {bregs[slot][1].x, bregs[slot][1].y};               \
    _Pragma("unroll")                                                         \
    for (int j_ = 0; j_ < 4; ++j_) {                                          \
      int p_ = 4 * pq + j_;                                                   \
      int cc_ = (2 * cp) ^ (SWZ(p_) << 3);                                    \
      unsigned int lo_ = (w0_[j_ >> 1] >> ((j_ & 1) * 16)) & 0xffffu;         \
      unsigned int hi_ = (w1_[j_ >> 1] >> ((j_ & 1) * 16)) & 0xffffu;         \
      *(unsigned int*)&B_lds[buf][p_ * 32 + cc_] = lo_ | (hi_ << 16);         \
    }                                                                         \
  } while (0)

  // ---- prologue: panels 0,1 in flight (8 vm ops)
  STAGE_A(0, 0);
  LOAD_B(0, 0);
  STAGE_A(1, 1);
  LOAD_B(1, 1);

  f32x4 acc[4][4];
#pragma unroll
  for (int mb = 0; mb < 4; ++mb)
#pragma unroll
    for (int nb = 0; nb < 4; ++nb) acc[mb][nb] = (f32x4){0.f, 0.f, 0.f, 0.f};

  // LDS read offsets (elements)
  int aofs[4];
#pragma unroll
  for (int mb = 0; mb < 4; ++mb) aofs[mb] = ((wm * 4 + mb) * 64 + lane) * 8;
  int bofs[4];
#pragma unroll
  for (int nb = 0; nb < 4; ++nb) {
    int pp = wn * 64 + nb * 16 + (lane & 15);
    bofs[nb] = pp * 32 + (((lane >> 4) * 8) ^ (SWZ(pp) << 3));
  }

  // drain panel 0 (first 4 of 8), publish B(0)
  asm volatile("s_waitcnt vmcnt(4)" ::: "memory");
  WRITE_B(0, 0);
  asm volatile("s_waitcnt lgkmcnt(0)" ::: "memory");
  __builtin_amdgcn_s_barrier();              // panel 0 published

#pragma unroll
  for (int kb = 0; kb < 8; ++kb) {
    const int cur = kb % 3;
    const int n1 = (kb + 1) % 3;
    // 1. issue panel kb+2 (buf n2 = (kb+2)%3 == (kb-1)%3, released at barrier kb-1)
    if (kb < 6) {
      STAGE_A(kb + 2, (kb + 2) % 3);
      LOAD_B(kb + 2, (kb + 2) % 3);
      __builtin_amdgcn_sched_barrier(0);
    }
    // 2. read fragments of panel kb (published)
    short8 af[4], bfr[4];
#pragma unroll
    for (int mb = 0; mb < 4; ++mb)
      af[mb] = *(const short8*)(&A_lds[cur][0] + aofs[mb]);
#pragma unroll
    for (int nb = 0; nb < 4; ++nb)
      bfr[nb] = *(const short8*)(&B_lds[cur][0] + bofs[nb]);
    // 3. wait panel kb+1 loads, publish its B into buf n1 (released at barrier kb-2)
    if (kb < 6) {
      asm volatile("s_waitcnt vmcnt(4)" ::: "memory");
      WRITE_B(n1, n1);
    } else if (kb == 6) {
      asm volatile("s_waitcnt vmcnt(0)" ::: "memory");
      WRITE_B(n1, n1);
    }
    // 4. all LDS ops (frag reads + B writes) complete
    asm volatile("s_waitcnt lgkmcnt(0)" ::: "memory");
    __builtin_amdgcn_sched_barrier(0);
    // 5. MFMA on panel kb
#pragma unroll
    for (int mb = 0; mb < 4; ++mb)
#pragma unroll
      for (int nb = 0; nb < 4; ++nb)
        acc[mb][nb] = __builtin_amdgcn_mfma_f32_16x16x32_bf16(
            af[mb], bfr[nb], acc[mb][nb], 0, 0, 0);
    // 6. single barrier: publishes panel kb+1, releases buf cur
    if (kb < 7) __builtin_amdgcn_s_barrier();
  }

  // ---- epilogue: bias, y store (bf16), GN partials (no atomics)
  // C/D layout: col(p) = lane&15, row(o) = (lane>>4)*4 + reg
  float psum[2] = {0.f, 0.f}, psq[2] = {0.f, 0.f};
  int orl = (lane >> 4) * 4;
  int pl = lane & 15;
  const size_t ybase = (size_t)bs * CC * HWSZ + p0 + wn * 64;
  int obase = wm * 64;
#pragma unroll
  for (int mb = 0; mb < 4; ++mb) {
    int gi = mb >> 1;                        // wave covers 2 GN groups (64 ch)
#pragma unroll
    for (int r = 0; r < 4; ++r) {
      int o = obase + mb * 16 + orl + r;
      float pb = proj_b[o];
      unsigned short* yrow = yb + ybase + (size_t)o * HWSZ + pl;
#pragma unroll
      for (int nb = 0; nb < 4; ++nb) {
        float v = acc[mb][nb][r] + pb;
        yrow[nb * 16] = f2bf(v);
        psum[gi] += v;
        psq[gi] += v * v;
      }
    }
  }
#pragma unroll
  for (int off = 32; off > 0; off >>= 1) {
#pragma unroll
    for (int k = 0; k < 2; ++k) {
      psum[k] += __shfl_down(psum[k], off, 64);
      psq[k] += __shfl_down(psq[k], off, 64);
    }
  }
  if (lane == 0) {
#pragma unroll
    for (int k = 0; k < 2; ++k) {
      int bg = bs * 8 + wm * 2 + k;
      part[(size_t)bg * 256 + pt * 2 + wn] = psum[k];
      part[32768 + (size_t)bg * 256 + pt * 2 + wn] = psq[k];
    }
  }
#undef STAGE_A
#undef LOAD_B
#undef WRITE_B
}

// ---------------------------------------------------------------------------
// K4.5: reduce GN partials (256 per group) -> stats[bg], stats[128+bg]
// ---------------------------------------------------------------------------
__global__ __launch_bounds__(256) void reduce_kernel(
    const float* __restrict__ part, float* __restrict__ stats) {
  int bg = blockIdx.x;             // 0..127 = bs*8+g
  int t = threadIdx.x;
  float s = part[(size_t)bg * 256 + t];
  float q = part[32768 + (size_t)bg * 256 + t];
#pragma unroll
  for (int off = 32; off > 0; off >>= 1) {
    s += __shfl_down(s, off, 64);
    q += __shfl_down(q, off, 64);
  }
  __shared__ float ls[8];
  if ((t & 63) == 0) { ls[t >> 6] = s; ls[4 + (t >> 6)] = q; }
  __syncthreads();
  if (t == 0) stats[bg] = ls[0] + ls[1] + ls[2] + ls[3];
  if (t == 64) stats[128 + bg] = ls[4] + ls[5] + ls[6] + ls[7];
}

// ---------------------------------------------------------------------------
// K5: GroupNorm affine + exact GELU + residual. Reads bf16 y, writes fp32 out.
// ---------------------------------------------------------------------------
__global__ __launch_bounds__(256) void out_kernel(
    const float* __restrict__ x, const unsigned short* __restrict__ yb,
    const float* __restrict__ stats, const float* __restrict__ gamma,
    const float* __restrict__ beta, float* __restrict__ out) {
  int plane = blockIdx.x;
  int b = plane >> 8, c = plane & 255, g = c >> 5;
  const float inv_n = 1.0f / (32.0f * (float)HWSZ);
  float mean = stats[b * 8 + g] * inv_n;
  float var = stats[128 + b * 8 + g] * inv_n - mean * mean;
  float rstd = rsqrtf(var + EPSV);
  float scale = gamma[c] * rstd;
  float shift = beta[c] - mean * scale;

  const size_t base = (size_t)plane * HWSZ;
  for (int i = threadIdx.x; i < HWSZ / 8; i += 256) {
    uint4 yv = *(const uint4*)(yb + base + 8 * (size_t)i);
    float4 x0 = *(const float4*)(x + base + 8 * (size_t)i);
    float4 x1 = *(const float4*)(x + base + 8 * (size_t)i + 4);
    unsigned int yw[4] = {yv.x, yv.y, yv.z, yv.w};
    float r[8];
    float xr[8] = {x0.x, x0.y, x0.z, x0.w, x1.x, x1.y, x1.z, x1.w};
#pragma unroll
    for (int k = 0; k < 8; ++k) {
      unsigned int h = (yw[k >> 1] >> ((k & 1) * 16)) & 0xffffu;
      float t = bf2f(h) * scale + shift;
      float ge = 0.5f * t * (1.0f + erff(t * 0.70710678118654752f));
      r[k] = ge + xr[k];
    }
    *(float4*)(out + base + 8 * (size_t)i) = make_float4(r[0], r[1], r[2], r[3]);
    *(float4*)(out + base + 8 * (size_t)i + 4) = make_float4(r[4], r[5], r[6], r[7]);
  }
}

// ---------------------------------------------------------------------------
extern "C" void kernel_launch(void* const* d_in, const int* in_sizes, int n_in,
                              void* d_out, int out_size, void* d_ws, size_t ws_size,
                              hipStream_t stream) {
  const float* x      = (const float*)d_in[0];
  const float* fbank  = (const float*)d_in[1];   // [NF,1,7,7]
  const float* sel_w  = (const float*)d_in[2];   // [NF,C]
  const float* sel_b  = (const float*)d_in[3];   // [NF]
  const float* proj_w = (const float*)d_in[4];   // [C,C,1,1]
  const float* proj_b = (const float*)d_in[5];   // [C]
  const float* gamma  = (const float*)d_in[6];   // [C]
  const float* beta   = (const float*)d_in[7];   // [C]
  float* out = (float*)d_out;

  // ws layout: fb bf16 [B*C*HW] | yb bf16 [B*C*HW] (distinct: gemm reads fb!)
  //            | ap bf16 [65536] | pooled | combined | stats | part[65536]
  unsigned short* fb  = (unsigned short*)d_ws;
  unsigned short* yb  = fb + (size_t)BB * CC * HWSZ;
  unsigned short* apk = yb + (size_t)BB * CC * HWSZ;
  float* pooled   = (float*)(apk + 65536);
  float* combined = pooled + BB * CC;
  float* stats    = combined + BB * 64;
  float* part     = stats + 256;

  hipLaunchKernelGGL(pool_pack_kernel, dim3(BB * CC + 256), dim3(256), 0, stream,
                     x, proj_w, pooled, apk);
  hipLaunchKernelGGL(selector_kernel, dim3(1), dim3(256), 0, stream,
                     pooled, sel_w, sel_b, fbank, combined);
  hipLaunchKernelGGL(dwconv_kernel, dim3(BB * CC, HH / TR), dim3(256), 0, stream,
                     x, combined, fb);
  hipLaunchKernelGGL(gemm_kernel, dim3(BB * 128), dim3(512), 0, stream,
                     fb, apk, proj_b, yb, part);
  hipLaunchKernelGGL(reduce_kernel, dim3(128), dim3(256), 0, stream, part, stats);
  hipLaunchKernelGGL(out_kernel, dim3(BB * CC), dim3(256), 0, stream,
                     x, yb, stats, gamma, beta, out);
}

// Round 14
// 419.100 us; speedup vs baseline: 1.4182x; 1.0035x over previous
//
#include <hip/hip_runtime.h>
#include <math.h>

// Problem constants
#define BB 16
#define CC 256
#define HH 128
#define WW 128
#define HWSZ 16384        // H*W
#define NF 8
#define EPSV 1e-5f

typedef __attribute__((ext_vector_type(8))) short short8;   // 8 bf16 = 4 VGPRs
typedef __attribute__((ext_vector_type(4))) float f32x4;

static __device__ __forceinline__ unsigned short f2bf(float f) {
  unsigned int u = __float_as_uint(f);
  u += 0x7fffu + ((u >> 16) & 1u);       // round-to-nearest-even
  return (unsigned short)(u >> 16);
}

static __device__ __forceinline__ float bf2f(unsigned int h) {
  return __uint_as_float(h << 16);
}

static __device__ __forceinline__ void gload_lds16(const unsigned short* g,
                                                   unsigned short* l) {
  __builtin_amdgcn_global_load_lds(
      (const __attribute__((address_space(1))) void*)(size_t)g,
      (__attribute__((address_space(3))) void*)(unsigned)(size_t)l, 16, 0, 0);
}

// ---------------------------------------------------------------------------
// K1: fused  (a) pooled[b,c] = mean over HW   (blocks 0..4095)
//            (b) pack proj_w -> bf16 A-frag order (blocks 4096..4351)
// ---------------------------------------------------------------------------
__global__ __launch_bounds__(256) void pool_pack_kernel(
    const float* __restrict__ x, const float* __restrict__ pw,
    float* __restrict__ pooled, unsigned short* __restrict__ ap) {
  int blk = blockIdx.x;
  int tid = threadIdx.x;
  if (blk >= BB * CC) {            // pack_a part
    int idx = (blk - BB * CC) * 256 + tid;      // 0..65535
    int e = idx & 7;
    int lane = (idx >> 3) & 63;
    int kb = (idx >> 9) & 7;
    int mb = idx >> 12;
    int o = mb * 16 + (lane & 15);
    int c = kb * 32 + (lane >> 4) * 8 + e;
    ap[idx] = f2bf(pw[o * 256 + c]);
    return;
  }
  // pool part
  const float4* xp = (const float4*)(x + (size_t)blk * HWSZ);
  float s = 0.f;
#pragma unroll
  for (int i = 0; i < 16; ++i) {
    float4 v = xp[tid + i * 256];
    s += v.x + v.y + v.z + v.w;
  }
#pragma unroll
  for (int off = 32; off > 0; off >>= 1) s += __shfl_down(s, off, 64);
  __shared__ float ls[4];
  if ((tid & 63) == 0) ls[tid >> 6] = s;
  __syncthreads();
  if (tid == 0) pooled[blk] = (ls[0] + ls[1] + ls[2] + ls[3]) * (1.0f / 16384.0f);
}

// ---------------------------------------------------------------------------
// K2: selector: GAP -> linear -> softmax -> mix filter bank.
// ---------------------------------------------------------------------------
__global__ __launch_bounds__(256) void selector_kernel(
    const float* __restrict__ pooled, const float* __restrict__ sel_w,
    const float* __restrict__ sel_b, const float* __restrict__ fbank,
    float* __restrict__ combined) {
  int tid = threadIdx.x;
  __shared__ float lg[BB][NF];
  __shared__ float wsm[BB][NF];
  if (tid < BB * NF) {
    int b = tid >> 3, n = tid & 7;
    const float* p = pooled + b * CC;
    const float* w = sel_w + n * CC;
    float d = sel_b[n];
    for (int c = 0; c < CC; c += 4) {
      d += p[c] * w[c] + p[c + 1] * w[c + 1] + p[c + 2] * w[c + 2] + p[c + 3] * w[c + 3];
    }
    lg[b][n] = d;
  }
  __syncthreads();
  if (tid < BB) {
    int b = tid;
    float m = lg[b][0];
#pragma unroll
    for (int n = 1; n < NF; ++n) m = fmaxf(m, lg[b][n]);
    float e[NF];
    float s = 0.f;
#pragma unroll
    for (int n = 0; n < NF; ++n) { e[n] = expf(lg[b][n] - m); s += e[n]; }
    float inv = 1.0f / s;
#pragma unroll
    for (int n = 0; n < NF; ++n) wsm[b][n] = e[n] * inv;
  }
  __syncthreads();
  for (int i = tid; i < BB * 49; i += 256) {
    int b = i / 49, j = i % 49;
    float acc = 0.f;
#pragma unroll
    for (int n = 0; n < NF; ++n) acc += wsm[b][n] * fbank[n * 49 + j];
    combined[b * 64 + j] = acc;
  }
}

// ---------------------------------------------------------------------------
// K3: depthwise 7x7 conv, per-sample filter; fp32 compute, bf16 output.
// ---------------------------------------------------------------------------
#define TR 32
__global__ __launch_bounds__(256) void dwconv_kernel(
    const float* __restrict__ x, const float* __restrict__ combined,
    unsigned short* __restrict__ fbp) {
  int plane = blockIdx.x;          // b*256 + c
  int rt = blockIdx.y;             // 0..3
  int b = plane >> 8;
  int r0 = rt * TR;
  int tid = threadIdx.x;

  __shared__ float xs[TR + 6][136];

  float kf[49];
  {
    const float* cb = combined + b * 64;
#pragma unroll
    for (int i = 0; i < 49; ++i) kf[i] = cb[i];
  }

  const size_t pbase = (size_t)plane * HWSZ;
  for (int idx = tid; idx < (TR + 6) * 34; idx += 256) {
    int row = idx / 34;
    int seg = idx % 34;
    int r = r0 - 3 + row;
    int c = seg * 4 - 4;
    float4 v = make_float4(0.f, 0.f, 0.f, 0.f);
    if (r >= 0 && r < HH && c >= 0 && c < WW) {
      v = *(const float4*)(x + pbase + (size_t)r * WW + c);
    }
    *(float4*)&xs[row][seg * 4] = v;
  }
  __syncthreads();

  int cg = tid & 31;
  int rg = tid >> 5;
  float acc[4][4] = {};

#pragma unroll
  for (int ri = 0; ri < 10; ++ri) {
    int lrow = 4 * rg + ri;
    float xr[12];
#pragma unroll
    for (int s = 0; s < 3; ++s)
      *(float4*)&xr[4 * s] = *(const float4*)&xs[lrow][cg * 4 + 4 * s];
#pragma unroll
    for (int orr = 0; orr < 4; ++orr) {
      int dy = ri - orr;
      if (dy < 0 || dy > 6) continue;
#pragma unroll
      for (int oc = 0; oc < 4; ++oc) {
#pragma unroll
        for (int dx = 0; dx < 7; ++dx) {
          acc[orr][oc] += xr[oc + dx + 1] * kf[dy * 7 + dx];
        }
      }
    }
  }

#pragma unroll
  for (int orr = 0; orr < 4; ++orr) {
    ushort4 sv;
    sv.x = f2bf(acc[orr][0]);
    sv.y = f2bf(acc[orr][1]);
    sv.z = f2bf(acc[orr][2]);
    sv.w = f2bf(acc[orr][3]);
    *(ushort4*)(fbp + pbase + (size_t)(r0 + 4 * rg + orr) * WW + 4 * cg) = sv;
  }
}

// ---------------------------------------------------------------------------
// K4: 1x1 conv as bf16 MFMA GEMM — in-kernel B repack, 3-buffer LDS pipeline,
//     ONE barrier per K-step, B register-prefetch THREE iterations deep.
//     Block = 256 o x 128 p, 512 thr (8 waves = 4 wm x 2 wn, each 64o x 64p).
//     r13 stalled ~500cy/iter: vmcnt(4) waited on B loads issued only 1 iter
//     (~350cy) earlier vs ~900cy HBM latency. Now LOAD_B(kb+3) (bregs mod 4)
//     so every wait targets loads >= 2-3 iters old. FIFO (prologue order
//     A0,B0,A1,B1,B2; per-iter A(kb+2) then B(kb+3)): vmcnt(6) kb<=4,
//     vmcnt(4) kb=5, vmcnt(0) kb=6.
// ---------------------------------------------------------------------------
#define SWZ(p) ((((p) >> 1) ^ ((p) >> 4)) & 3)

__global__ __launch_bounds__(512, 2) void gemm_kernel(
    const unsigned short* __restrict__ fb, const unsigned short* __restrict__ ap,
    const float* __restrict__ proj_b, unsigned short* __restrict__ yb,
    float* __restrict__ part) {
  int bid = blockIdx.x;            // bs*128 + pt
  int bs = bid >> 7;
  int pt = bid & 127;
  int p0 = pt * 128;
  int tid = threadIdx.x;
  int lane = tid & 63;
  int wave = tid >> 6;
  int wm = wave >> 1;              // 0..3 -> o 64-block
  int wn = wave & 1;               // 0..1 -> p 64-block

  __shared__ __align__(16) unsigned short A_lds[3][8192];  // 3 x 16 KB
  __shared__ __align__(16) unsigned short B_lds[3][4096];  // 3 x 8 KB

  // --- A staging: thread t stages MB=(t>>6) and MB=8+(t>>6)
  const unsigned short* asrc0 =
      ap + (size_t)(tid >> 6) * 4096 + (size_t)(tid & 63) * 8;
  unsigned short* adst = &A_lds[0][0] + (size_t)tid * 8;

  // --- B staging: thread t reg-loads c rows {2cp,2cp+1}, p = 4pq..4pq+3
  int cp = tid >> 5;               // 0..15
  int pq = tid & 31;               // 0..31
  const unsigned short* bsrc0 =
      fb + ((size_t)bs * CC + 2 * cp) * HWSZ + p0 + 4 * pq;

  uint2 bregs[4][2];               // [slot = kb&3][row]

#define STAGE_A(kb, buf)                                                      \
  do {                                                                        \
    gload_lds16(asrc0 + (size_t)(kb) * 512, adst + (size_t)(buf) * 8192);     \
    gload_lds16(asrc0 + 32768 + (size_t)(kb) * 512,                           \
                adst + (size_t)(buf) * 8192 + 4096);                          \
  } while (0)
#define LOAD_B(kb, slot)                                                      \
  do {                                                                        \
    const unsigned short* s_ = bsrc0 + (size_t)(kb) * 32 * HWSZ;              \
    bregs[slot][0] = *(const uint2*)s_;                                       \
    bregs[slot][1] = *(const uint2*)(s_ + HWSZ);                              \
  } while (0)
#define WRITE_B(slot, buf)                                                    \
  do {                                                                        \
    unsigned int w0_[2] = {bregs[slot][0].x, bregs[slot][0].y};               \
    unsigned int w1_[2] = {bregs[slot][1].x, bregs[slot][1].y};               \
    _Pragma("unroll")                                                         \
    for (int j_ = 0; j_ < 4; ++j_) {                                          \
      int p_ = 4 * pq + j_;                                                   \
      int cc_ = (2 * cp) ^ (SWZ(p_) << 3);                                    \
      unsigned int lo_ = (w0_[j_ >> 1] >> ((j_ & 1) * 16)) & 0xffffu;         \
      unsigned int hi_ = (w1_[j_ >> 1] >> ((j_ & 1) * 16)) & 0xffffu;         \
      *(unsigned int*)&B_lds[buf][p_ * 32 + cc_] = lo_ | (hi_ << 16);         \
    }                                                                         \
  } while (0)

  // ---- prologue: FIFO order A0,B0,A1,B1,B2 (10 vm ops)
  STAGE_A(0, 0);
  LOAD_B(0, 0);
  STAGE_A(1, 1);
  LOAD_B(1, 1);
  LOAD_B(2, 2);

  f32x4 acc[4][4];
#pragma unroll
  for (int mb = 0; mb < 4; ++mb)
#pragma unroll
    for (int nb = 0; nb < 4; ++nb) acc[mb][nb] = (f32x4){0.f, 0.f, 0.f, 0.f};

  // LDS read offsets (elements)
  int aofs[4];
#pragma unroll
  for (int mb = 0; mb < 4; ++mb) aofs[mb] = ((wm * 4 + mb) * 64 + lane) * 8;
  int bofs[4];
#pragma unroll
  for (int nb = 0; nb < 4; ++nb) {
    int pp = wn * 64 + nb * 16 + (lane & 15);
    bofs[nb] = pp * 32 + (((lane >> 4) * 8) ^ (SWZ(pp) << 3));
  }

  // retire A0+B0 (oldest 4 of 10), publish B(0)
  asm volatile("s_waitcnt vmcnt(6)" ::: "memory");
  WRITE_B(0, 0);
  asm volatile("s_waitcnt lgkmcnt(0)" ::: "memory");
  __builtin_amdgcn_s_barrier();              // panel 0 published

#pragma unroll
  for (int kb = 0; kb < 8; ++kb) {
    const int cur = kb % 3;
    const int n1 = (kb + 1) % 3;
    // 1. issue A(kb+2) into LDS buf (kb+2)%3 (released at barrier kb-1),
    //    then B(kb+3) into reg slot (kb+3)&3
    if (kb < 6) STAGE_A(kb + 2, (kb + 2) % 3);
    if (kb < 5) LOAD_B(kb + 3, (kb + 3) & 3);
    if (kb < 6) __builtin_amdgcn_sched_barrier(0);
    // 2. read fragments of panel kb (published)
    short8 af[4], bfr[4];
#pragma unroll
    for (int mb = 0; mb < 4; ++mb)
      af[mb] = *(const short8*)(&A_lds[cur][0] + aofs[mb]);
#pragma unroll
    for (int nb = 0; nb < 4; ++nb)
      bfr[nb] = *(const short8*)(&B_lds[cur][0] + bofs[nb]);
    // 3. retire A(kb+1) [LDS] + B(kb+1) [regs, issued kb-2], publish B(kb+1)
    if (kb <= 4) {
      asm volatile("s_waitcnt vmcnt(6)" ::: "memory");
      WRITE_B((kb + 1) & 3, n1);
    } else if (kb == 5) {
      asm volatile("s_waitcnt vmcnt(4)" ::: "memory");
      WRITE_B((kb + 1) & 3, n1);
    } else if (kb == 6) {
      asm volatile("s_waitcnt vmcnt(0)" ::: "memory");
      WRITE_B((kb + 1) & 3, n1);
    }
    // 4. all LDS ops (frag reads + B writes) complete
    asm volatile("s_waitcnt lgkmcnt(0)" ::: "memory");
    __builtin_amdgcn_sched_barrier(0);
    // 5. MFMA on panel kb
#pragma unroll
    for (int mb = 0; mb < 4; ++mb)
#pragma unroll
      for (int nb = 0; nb < 4; ++nb)
        acc[mb][nb] = __builtin_amdgcn_mfma_f32_16x16x32_bf16(
            af[mb], bfr[nb], acc[mb][nb], 0, 0, 0);
    // 6. single barrier: publishes panel kb+1, releases buf cur
    if (kb < 7) __builtin_amdgcn_s_barrier();
  }

  // ---- epilogue: bias, y store (bf16), GN partials (no atomics)
  // C/D layout: col(p) = lane&15, row(o) = (lane>>4)*4 + reg
  float psum[2] = {0.f, 0.f}, psq[2] = {0.f, 0.f};
  int orl = (lane >> 4) * 4;
  int pl = lane & 15;
  const size_t ybase = (size_t)bs * CC * HWSZ + p0 + wn * 64;
  int obase = wm * 64;
#pragma unroll
  for (int mb = 0; mb < 4; ++mb) {
    int gi = mb >> 1;                        // wave covers 2 GN groups (64 ch)
#pragma unroll
    for (int r = 0; r < 4; ++r) {
      int o = obase + mb * 16 + orl + r;
      float pb = proj_b[o];
      unsigned short* yrow = yb + ybase + (size_t)o * HWSZ + pl;
#pragma unroll
      for (int nb = 0; nb < 4; ++nb) {
        float v = acc[mb][nb][r] + pb;
        yrow[nb * 16] = f2bf(v);
        psum[gi] += v;
        psq[gi] += v * v;
      }
    }
  }
#pragma unroll
  for (int off = 32; off > 0; off >>= 1) {
#pragma unroll
    for (int k = 0; k < 2; ++k) {
      psum[k] += __shfl_down(psum[k], off, 64);
      psq[k] += __shfl_down(psq[k], off, 64);
    }
  }
  if (lane == 0) {
#pragma unroll
    for (int k = 0; k < 2; ++k) {
      int bg = bs * 8 + wm * 2 + k;
      part[(size_t)bg * 256 + pt * 2 + wn] = psum[k];
      part[32768 + (size_t)bg * 256 + pt * 2 + wn] = psq[k];
    }
  }
#undef STAGE_A
#undef LOAD_B
#undef WRITE_B
}

// ---------------------------------------------------------------------------
// K4.5: reduce GN partials (256 per group) -> stats[bg], stats[128+bg]
// ---------------------------------------------------------------------------
__global__ __launch_bounds__(256) void reduce_kernel(
    const float* __restrict__ part, float* __restrict__ stats) {
  int bg = blockIdx.x;             // 0..127 = bs*8+g
  int t = threadIdx.x;
  float s = part[(size_t)bg * 256 + t];
  float q = part[32768 + (size_t)bg * 256 + t];
#pragma unroll
  for (int off = 32; off > 0; off >>= 1) {
    s += __shfl_down(s, off, 64);
    q += __shfl_down(q, off, 64);
  }
  __shared__ float ls[8];
  if ((t & 63) == 0) { ls[t >> 6] = s; ls[4 + (t >> 6)] = q; }
  __syncthreads();
  if (t == 0) stats[bg] = ls[0] + ls[1] + ls[2] + ls[3];
  if (t == 64) stats[128 + bg] = ls[4] + ls[5] + ls[6] + ls[7];
}

// ---------------------------------------------------------------------------
// K5: GroupNorm affine + exact GELU + residual. Reads bf16 y, writes fp32 out.
// ---------------------------------------------------------------------------
__global__ __launch_bounds__(256) void out_kernel(
    const float* __restrict__ x, const unsigned short* __restrict__ yb,
    const float* __restrict__ stats, const float* __restrict__ gamma,
    const float* __restrict__ beta, float* __restrict__ out) {
  int plane = blockIdx.x;
  int b = plane >> 8, c = plane & 255, g = c >> 5;
  const float inv_n = 1.0f / (32.0f * (float)HWSZ);
  float mean = stats[b * 8 + g] * inv_n;
  float var = stats[128 + b * 8 + g] * inv_n - mean * mean;
  float rstd = rsqrtf(var + EPSV);
  float scale = gamma[c] * rstd;
  float shift = beta[c] - mean * scale;

  const size_t base = (size_t)plane * HWSZ;
  for (int i = threadIdx.x; i < HWSZ / 8; i += 256) {
    uint4 yv = *(const uint4*)(yb + base + 8 * (size_t)i);
    float4 x0 = *(const float4*)(x + base + 8 * (size_t)i);
    float4 x1 = *(const float4*)(x + base + 8 * (size_t)i + 4);
    unsigned int yw[4] = {yv.x, yv.y, yv.z, yv.w};
    float r[8];
    float xr[8] = {x0.x, x0.y, x0.z, x0.w, x1.x, x1.y, x1.z, x1.w};
#pragma unroll
    for (int k = 0; k < 8; ++k) {
      unsigned int h = (yw[k >> 1] >> ((k & 1) * 16)) & 0xffffu;
      float t = bf2f(h) * scale + shift;
      float ge = 0.5f * t * (1.0f + erff(t * 0.70710678118654752f));
      r[k] = ge + xr[k];
    }
    *(float4*)(out + base + 8 * (size_t)i) = make_float4(r[0], r[1], r[2], r[3]);
    *(float4*)(out + base + 8 * (size_t)i + 4) = make_float4(r[4], r[5], r[6], r[7]);
  }
}

// ---------------------------------------------------------------------------
extern "C" void kernel_launch(void* const* d_in, const int* in_sizes, int n_in,
                              void* d_out, int out_size, void* d_ws, size_t ws_size,
                              hipStream_t stream) {
  const float* x      = (const float*)d_in[0];
  const float* fbank  = (const float*)d_in[1];   // [NF,1,7,7]
  const float* sel_w  = (const float*)d_in[2];   // [NF,C]
  const float* sel_b  = (const float*)d_in[3];   // [NF]
  const float* proj_w = (const float*)d_in[4];   // [C,C,1,1]
  const float* proj_b = (const float*)d_in[5];   // [C]
  const float* gamma  = (const float*)d_in[6];   // [C]
  const float* beta   = (const float*)d_in[7];   // [C]
  float* out = (float*)d_out;

  // ws layout: fb bf16 [B*C*HW] | yb bf16 [B*C*HW] (distinct: gemm reads fb!)
  //            | ap bf16 [65536] | pooled | combined | stats | part[65536]
  unsigned short* fb  = (unsigned short*)d_ws;
  unsigned short* yb  = fb + (size_t)BB * CC * HWSZ;
  unsigned short* apk = yb + (size_t)BB * CC * HWSZ;
  float* pooled   = (float*)(apk + 65536);
  float* combined = pooled + BB * CC;
  float* stats    = combined + BB * 64;
  float* part     = stats + 256;

  hipLaunchKernelGGL(pool_pack_kernel, dim3(BB * CC + 256), dim3(256), 0, stream,
                     x, proj_w, pooled, apk);
  hipLaunchKernelGGL(selector_kernel, dim3(1), dim3(256), 0, stream,
                     pooled, sel_w, sel_b, fbank, combined);
  hipLaunchKernelGGL(dwconv_kernel, dim3(BB * CC, HH / TR), dim3(256), 0, stream,
                     x, combined, fb);
  hipLaunchKernelGGL(gemm_kernel, dim3(BB * 128), dim3(512), 0, stream,
                     fb, apk, proj_b, yb, part);
  hipLaunchKernelGGL(reduce_kernel, dim3(128), dim3(256), 0, stream, part, stats);
  hipLaunchKernelGGL(out_kernel, dim3(BB * CC), dim3(256), 0, stream,
                     x, yb, stats, gamma, beta, out);
}

// Round 15
// 406.313 us; speedup vs baseline: 1.4629x; 1.0315x over previous
//
#include <hip/hip_runtime.h>
#include <math.h>

// Problem constants
#define BB 16
#define CC 256
#define HH 128
#define WW 128
#define HWSZ 16384        // H*W
#define NF 8
#define EPSV 1e-5f

typedef __attribute__((ext_vector_type(8))) short short8;   // 8 bf16 = 4 VGPRs
typedef __attribute__((ext_vector_type(4))) float f32x4;

static __device__ __forceinline__ unsigned short f2bf(float f) {
  unsigned int u = __float_as_uint(f);
  u += 0x7fffu + ((u >> 16) & 1u);       // round-to-nearest-even
  return (unsigned short)(u >> 16);
}

static __device__ __forceinline__ float bf2f(unsigned int h) {
  return __uint_as_float(h << 16);
}

static __device__ __forceinline__ void gload_lds16(const unsigned short* g,
                                                   unsigned short* l) {
  __builtin_amdgcn_global_load_lds(
      (const __attribute__((address_space(1))) void*)(size_t)g,
      (__attribute__((address_space(3))) void*)(unsigned)(size_t)l, 16, 0, 0);
}

// ---------------------------------------------------------------------------
// K1: fused  (a) pooled[b,c] = mean over HW   (blocks 0..4095)
//            (b) pack proj_w -> bf16 A-frag order (blocks 4096..4351)
// ---------------------------------------------------------------------------
__global__ __launch_bounds__(256) void pool_pack_kernel(
    const float* __restrict__ x, const float* __restrict__ pw,
    float* __restrict__ pooled, unsigned short* __restrict__ ap) {
  int blk = blockIdx.x;
  int tid = threadIdx.x;
  if (blk >= BB * CC) {            // pack_a part
    int idx = (blk - BB * CC) * 256 + tid;      // 0..65535
    int e = idx & 7;
    int lane = (idx >> 3) & 63;
    int kb = (idx >> 9) & 7;
    int mb = idx >> 12;
    int o = mb * 16 + (lane & 15);
    int c = kb * 32 + (lane >> 4) * 8 + e;
    ap[idx] = f2bf(pw[o * 256 + c]);
    return;
  }
  // pool part
  const float4* xp = (const float4*)(x + (size_t)blk * HWSZ);
  float s = 0.f;
#pragma unroll
  for (int i = 0; i < 16; ++i) {
    float4 v = xp[tid + i * 256];
    s += v.x + v.y + v.z + v.w;
  }
#pragma unroll
  for (int off = 32; off > 0; off >>= 1) s += __shfl_down(s, off, 64);
  __shared__ float ls[4];
  if ((tid & 63) == 0) ls[tid >> 6] = s;
  __syncthreads();
  if (tid == 0) pooled[blk] = (ls[0] + ls[1] + ls[2] + ls[3]) * (1.0f / 16384.0f);
}

// ---------------------------------------------------------------------------
// K2: selector: GAP -> linear -> softmax -> mix filter bank.
// ---------------------------------------------------------------------------
__global__ __launch_bounds__(256) void selector_kernel(
    const float* __restrict__ pooled, const float* __restrict__ sel_w,
    const float* __restrict__ sel_b, const float* __restrict__ fbank,
    float* __restrict__ combined) {
  int tid = threadIdx.x;
  __shared__ float lg[BB][NF];
  __shared__ float wsm[BB][NF];
  if (tid < BB * NF) {
    int b = tid >> 3, n = tid & 7;
    const float* p = pooled + b * CC;
    const float* w = sel_w + n * CC;
    float d = sel_b[n];
    for (int c = 0; c < CC; c += 4) {
      d += p[c] * w[c] + p[c + 1] * w[c + 1] + p[c + 2] * w[c + 2] + p[c + 3] * w[c + 3];
    }
    lg[b][n] = d;
  }
  __syncthreads();
  if (tid < BB) {
    int b = tid;
    float m = lg[b][0];
#pragma unroll
    for (int n = 1; n < NF; ++n) m = fmaxf(m, lg[b][n]);
    float e[NF];
    float s = 0.f;
#pragma unroll
    for (int n = 0; n < NF; ++n) { e[n] = expf(lg[b][n] - m); s += e[n]; }
    float inv = 1.0f / s;
#pragma unroll
    for (int n = 0; n < NF; ++n) wsm[b][n] = e[n] * inv;
  }
  __syncthreads();
  for (int i = tid; i < BB * 49; i += 256) {
    int b = i / 49, j = i % 49;
    float acc = 0.f;
#pragma unroll
    for (int n = 0; n < NF; ++n) acc += wsm[b][n] * fbank[n * 49 + j];
    combined[b * 64 + j] = acc;
  }
}

// ---------------------------------------------------------------------------
// K3: depthwise 7x7 conv, per-sample filter; fp32 compute, bf16 output.
//     TR=64: halo refetch 70/64 = 1.09x (was 38/32 = 1.19x); LDS 38 KB.
//     Thread = 8 rows x 4 cols.
// ---------------------------------------------------------------------------
#define TR 64
__global__ __launch_bounds__(256) void dwconv_kernel(
    const float* __restrict__ x, const float* __restrict__ combined,
    unsigned short* __restrict__ fbp) {
  int plane = blockIdx.x;          // b*256 + c
  int rt = blockIdx.y;             // 0..1
  int b = plane >> 8;
  int r0 = rt * TR;
  int tid = threadIdx.x;

  __shared__ float xs[TR + 6][136];

  float kf[49];
  {
    const float* cb = combined + b * 64;
#pragma unroll
    for (int i = 0; i < 49; ++i) kf[i] = cb[i];
  }

  const size_t pbase = (size_t)plane * HWSZ;
  for (int idx = tid; idx < (TR + 6) * 34; idx += 256) {
    int row = idx / 34;            // 0..69
    int seg = idx % 34;
    int r = r0 - 3 + row;
    int c = seg * 4 - 4;
    float4 v = make_float4(0.f, 0.f, 0.f, 0.f);
    if (r >= 0 && r < HH && c >= 0 && c < WW) {
      v = *(const float4*)(x + pbase + (size_t)r * WW + c);
    }
    *(float4*)&xs[row][seg * 4] = v;
  }
  __syncthreads();

  int cg = tid & 31;               // col group: cols 4cg..4cg+3
  int rg = tid >> 5;               // row group: rows 8rg..8rg+7 (rel to r0)
  float acc[8][4] = {};

#pragma unroll
  for (int ri = 0; ri < 14; ++ri) {          // input rows 8rg-3 .. 8rg+10
    int lrow = 8 * rg + ri;                  // LDS row index
    float xr[12];
#pragma unroll
    for (int s = 0; s < 3; ++s)
      *(float4*)&xr[4 * s] = *(const float4*)&xs[lrow][cg * 4 + 4 * s];
#pragma unroll
    for (int orr = 0; orr < 8; ++orr) {
      int dy = ri - orr;
      if (dy < 0 || dy > 6) continue;        // compile-time pruned
#pragma unroll
      for (int oc = 0; oc < 4; ++oc) {
#pragma unroll
        for (int dx = 0; dx < 7; ++dx) {
          acc[orr][oc] += xr[oc + dx + 1] * kf[dy * 7 + dx];
        }
      }
    }
  }

#pragma unroll
  for (int orr = 0; orr < 8; ++orr) {
    ushort4 sv;
    sv.x = f2bf(acc[orr][0]);
    sv.y = f2bf(acc[orr][1]);
    sv.z = f2bf(acc[orr][2]);
    sv.w = f2bf(acc[orr][3]);
    *(ushort4*)(fbp + pbase + (size_t)(r0 + 8 * rg + orr) * WW + 4 * cg) = sv;
  }
}

// ---------------------------------------------------------------------------
// K4: 1x1 conv as bf16 MFMA GEMM — in-kernel B repack, 3-buffer LDS pipeline,
//     ONE barrier per K-step, B register-prefetch 3 deep, setprio'd MFMA (T5).
//     Block = 256 o x 128 p, 512 thr (8 waves = 4 wm x 2 wn, each 64o x 64p).
// ---------------------------------------------------------------------------
#define SWZ(p) ((((p) >> 1) ^ ((p) >> 4)) & 3)

__global__ __launch_bounds__(512, 2) void gemm_kernel(
    const unsigned short* __restrict__ fb, const unsigned short* __restrict__ ap,
    const float* __restrict__ proj_b, unsigned short* __restrict__ yb,
    float* __restrict__ part) {
  int bid = blockIdx.x;            // bs*128 + pt
  int bs = bid >> 7;
  int pt = bid & 127;
  int p0 = pt * 128;
  int tid = threadIdx.x;
  int lane = tid & 63;
  int wave = tid >> 6;
  int wm = wave >> 1;              // 0..3 -> o 64-block
  int wn = wave & 1;               // 0..1 -> p 64-block

  __shared__ __align__(16) unsigned short A_lds[3][8192];  // 3 x 16 KB
  __shared__ __align__(16) unsigned short B_lds[3][4096];  // 3 x 8 KB

  // --- A staging: thread t stages MB=(t>>6) and MB=8+(t>>6)
  const unsigned short* asrc0 =
      ap + (size_t)(tid >> 6) * 4096 + (size_t)(tid & 63) * 8;
  unsigned short* adst = &A_lds[0][0] + (size_t)tid * 8;

  // --- B staging: thread t reg-loads c rows {2cp,2cp+1}, p = 4pq..4pq+3
  int cp = tid >> 5;               // 0..15
  int pq = tid & 31;               // 0..31
  const unsigned short* bsrc0 =
      fb + ((size_t)bs * CC + 2 * cp) * HWSZ + p0 + 4 * pq;

  uint2 bregs[4][2];               // [slot = kb&3][row]

#define STAGE_A(kb, buf)                                                      \
  do {                                                                        \
    gload_lds16(asrc0 + (size_t)(kb) * 512, adst + (size_t)(buf) * 8192);     \
    gload_lds16(asrc0 + 32768 + (size_t)(kb) * 512,                           \
                adst + (size_t)(buf) * 8192 + 4096);                          \
  } while (0)
#define LOAD_B(kb, slot)                                                      \
  do {                                                                        \
    const unsigned short* s_ = bsrc0 + (size_t)(kb) * 32 * HWSZ;              \
    bregs[slot][0] = *(const uint2*)s_;                                       \
    bregs[slot][1] = *(const uint2*)(s_ + HWSZ);                              \
  } while (0)
#define WRITE_B(slot, buf)                                                    \
  do {                                                                        \
    unsigned int w0_[2] = {bregs[slot][0].x, bregs[slot][0].y};               \
    unsigned int w1_[2] = {bregs[slot][1].x, bregs[slot][1].y};               \
    _Pragma("unroll")                                                         \
    for (int j_ = 0; j_ < 4; ++j_) {                                          \
      int p_ = 4 * pq + j_;                                                   \
      int cc_ = (2 * cp) ^ (SWZ(p_) << 3);                                    \
      unsigned int lo_ = (w0_[j_ >> 1] >> ((j_ & 1) * 16)) & 0xffffu;         \
      unsigned int hi_ = (w1_[j_ >> 1] >> ((j_ & 1) * 16)) & 0xffffu;         \
      *(unsigned int*)&B_lds[buf][p_ * 32 + cc_] = lo_ | (hi_ << 16);         \
    }                                                                         \
  } while (0)

  // ---- prologue: FIFO order A0,B0,A1,B1,B2 (10 vm ops)
  STAGE_A(0, 0);
  LOAD_B(0, 0);
  STAGE_A(1, 1);
  LOAD_B(1, 1);
  LOAD_B(2, 2);

  f32x4 acc[4][4];
#pragma unroll
  for (int mb = 0; mb < 4; ++mb)
#pragma unroll
    for (int nb = 0; nb < 4; ++nb) acc[mb][nb] = (f32x4){0.f, 0.f, 0.f, 0.f};

  // LDS read offsets (elements)
  int aofs[4];
#pragma unroll
  for (int mb = 0; mb < 4; ++mb) aofs[mb] = ((wm * 4 + mb) * 64 + lane) * 8;
  int bofs[4];
#pragma unroll
  for (int nb = 0; nb < 4; ++nb) {
    int pp = wn * 64 + nb * 16 + (lane & 15);
    bofs[nb] = pp * 32 + (((lane >> 4) * 8) ^ (SWZ(pp) << 3));
  }

  // retire A0+B0 (oldest 4 of 10), publish B(0)
  asm volatile("s_waitcnt vmcnt(6)" ::: "memory");
  WRITE_B(0, 0);
  asm volatile("s_waitcnt lgkmcnt(0)" ::: "memory");
  __builtin_amdgcn_s_barrier();              // panel 0 published

#pragma unroll
  for (int kb = 0; kb < 8; ++kb) {
    const int cur = kb % 3;
    const int n1 = (kb + 1) % 3;
    // 1. issue A(kb+2) into LDS buf (kb+2)%3 (released at barrier kb-1),
    //    then B(kb+3) into reg slot (kb+3)&3
    if (kb < 6) STAGE_A(kb + 2, (kb + 2) % 3);
    if (kb < 5) LOAD_B(kb + 3, (kb + 3) & 3);
    if (kb < 6) __builtin_amdgcn_sched_barrier(0);
    // 2. read fragments of panel kb (published)
    short8 af[4], bfr[4];
#pragma unroll
    for (int mb = 0; mb < 4; ++mb)
      af[mb] = *(const short8*)(&A_lds[cur][0] + aofs[mb]);
#pragma unroll
    for (int nb = 0; nb < 4; ++nb)
      bfr[nb] = *(const short8*)(&B_lds[cur][0] + bofs[nb]);
    // 3. retire A(kb+1) [LDS] + B(kb+1) [regs, issued kb-2], publish B(kb+1)
    if (kb <= 4) {
      asm volatile("s_waitcnt vmcnt(6)" ::: "memory");
      WRITE_B((kb + 1) & 3, n1);
    } else if (kb == 5) {
      asm volatile("s_waitcnt vmcnt(4)" ::: "memory");
      WRITE_B((kb + 1) & 3, n1);
    } else if (kb == 6) {
      asm volatile("s_waitcnt vmcnt(0)" ::: "memory");
      WRITE_B((kb + 1) & 3, n1);
    }
    // 4. all LDS ops (frag reads + B writes) complete
    asm volatile("s_waitcnt lgkmcnt(0)" ::: "memory");
    __builtin_amdgcn_sched_barrier(0);
    // 5. MFMA on panel kb (T5: raise wave priority through the matrix cluster)
    __builtin_amdgcn_s_setprio(1);
#pragma unroll
    for (int mb = 0; mb < 4; ++mb)
#pragma unroll
      for (int nb = 0; nb < 4; ++nb)
        acc[mb][nb] = __builtin_amdgcn_mfma_f32_16x16x32_bf16(
            af[mb], bfr[nb], acc[mb][nb], 0, 0, 0);
    __builtin_amdgcn_s_setprio(0);
    // 6. single barrier: publishes panel kb+1, releases buf cur
    if (kb < 7) __builtin_amdgcn_s_barrier();
  }

  // ---- epilogue: bias, y store (bf16), GN partials (no atomics)
  // C/D layout: col(p) = lane&15, row(o) = (lane>>4)*4 + reg
  float psum[2] = {0.f, 0.f}, psq[2] = {0.f, 0.f};
  int orl = (lane >> 4) * 4;
  int pl = lane & 15;
  const size_t ybase = (size_t)bs * CC * HWSZ + p0 + wn * 64;
  int obase = wm * 64;
#pragma unroll
  for (int mb = 0; mb < 4; ++mb) {
    int gi = mb >> 1;                        // wave covers 2 GN groups (64 ch)
#pragma unroll
    for (int r = 0; r < 4; ++r) {
      int o = obase + mb * 16 + orl + r;
      float pb = proj_b[o];
      unsigned short* yrow = yb + ybase + (size_t)o * HWSZ + pl;
#pragma unroll
      for (int nb = 0; nb < 4; ++nb) {
        float v = acc[mb][nb][r] + pb;
        yrow[nb * 16] = f2bf(v);
        psum[gi] += v;
        psq[gi] += v * v;
      }
    }
  }
#pragma unroll
  for (int off = 32; off > 0; off >>= 1) {
#pragma unroll
    for (int k = 0; k < 2; ++k) {
      psum[k] += __shfl_down(psum[k], off, 64);
      psq[k] += __shfl_down(psq[k], off, 64);
    }
  }
  if (lane == 0) {
#pragma unroll
    for (int k = 0; k < 2; ++k) {
      int bg = bs * 8 + wm * 2 + k;
      part[(size_t)bg * 256 + pt * 2 + wn] = psum[k];
      part[32768 + (size_t)bg * 256 + pt * 2 + wn] = psq[k];
    }
  }
#undef STAGE_A
#undef LOAD_B
#undef WRITE_B
}

// ---------------------------------------------------------------------------
// K5: GroupNorm affine + exact GELU + residual, with IN-KERNEL stats reduce:
//     each block re-reduces its group's 256 partials (2 KB, L2-hot).
//     Reads bf16 y, writes fp32 out.
// ---------------------------------------------------------------------------
__global__ __launch_bounds__(256) void out_kernel(
    const float* __restrict__ x, const unsigned short* __restrict__ yb,
    const float* __restrict__ part, const float* __restrict__ gamma,
    const float* __restrict__ beta, float* __restrict__ out) {
  int plane = blockIdx.x;
  int b = plane >> 8, c = plane & 255, g = c >> 5;
  int bg = b * 8 + g;
  int t = threadIdx.x;

  // reduce this group's 256 partials (all threads participate)
  float s = part[(size_t)bg * 256 + t];
  float q = part[32768 + (size_t)bg * 256 + t];
#pragma unroll
  for (int off = 32; off > 0; off >>= 1) {
    s += __shfl_down(s, off, 64);
    q += __shfl_down(q, off, 64);
  }
  __shared__ float ls[8];
  if ((t & 63) == 0) { ls[t >> 6] = s; ls[4 + (t >> 6)] = q; }
  __syncthreads();
  float tsum = ls[0] + ls[1] + ls[2] + ls[3];
  float tsq = ls[4] + ls[5] + ls[6] + ls[7];

  const float inv_n = 1.0f / (32.0f * (float)HWSZ);
  float mean = tsum * inv_n;
  float var = tsq * inv_n - mean * mean;
  float rstd = rsqrtf(var + EPSV);
  float scale = gamma[c] * rstd;
  float shift = beta[c] - mean * scale;

  const size_t base = (size_t)plane * HWSZ;
  for (int i = t; i < HWSZ / 8; i += 256) {
    uint4 yv = *(const uint4*)(yb + base + 8 * (size_t)i);
    float4 x0 = *(const float4*)(x + base + 8 * (size_t)i);
    float4 x1 = *(const float4*)(x + base + 8 * (size_t)i + 4);
    unsigned int yw[4] = {yv.x, yv.y, yv.z, yv.w};
    float r[8];
    float xr[8] = {x0.x, x0.y, x0.z, x0.w, x1.x, x1.y, x1.z, x1.w};
#pragma unroll
    for (int k = 0; k < 8; ++k) {
      unsigned int h = (yw[k >> 1] >> ((k & 1) * 16)) & 0xffffu;
      float tv = bf2f(h) * scale + shift;
      float ge = 0.5f * tv * (1.0f + erff(tv * 0.70710678118654752f));
      r[k] = ge + xr[k];
    }
    *(float4*)(out + base + 8 * (size_t)i) = make_float4(r[0], r[1], r[2], r[3]);
    *(float4*)(out + base + 8 * (size_t)i + 4) = make_float4(r[4], r[5], r[6], r[7]);
  }
}

// ---------------------------------------------------------------------------
extern "C" void kernel_launch(void* const* d_in, const int* in_sizes, int n_in,
                              void* d_out, int out_size, void* d_ws, size_t ws_size,
                              hipStream_t stream) {
  const float* x      = (const float*)d_in[0];
  const float* fbank  = (const float*)d_in[1];   // [NF,1,7,7]
  const float* sel_w  = (const float*)d_in[2];   // [NF,C]
  const float* sel_b  = (const float*)d_in[3];   // [NF]
  const float* proj_w = (const float*)d_in[4];   // [C,C,1,1]
  const float* proj_b = (const float*)d_in[5];   // [C]
  const float* gamma  = (const float*)d_in[6];   // [C]
  const float* beta   = (const float*)d_in[7];   // [C]
  float* out = (float*)d_out;

  // ws layout: fb bf16 [B*C*HW] | yb bf16 [B*C*HW] (distinct: gemm reads fb!)
  //            | ap bf16 [65536] | pooled | combined | part[65536]
  unsigned short* fb  = (unsigned short*)d_ws;
  unsigned short* yb  = fb + (size_t)BB * CC * HWSZ;
  unsigned short* apk = yb + (size_t)BB * CC * HWSZ;
  float* pooled   = (float*)(apk + 65536);
  float* combined = pooled + BB * CC;
  float* part     = combined + BB * 64;

  hipLaunchKernelGGL(pool_pack_kernel, dim3(BB * CC + 256), dim3(256), 0, stream,
                     x, proj_w, pooled, apk);
  hipLaunchKernelGGL(selector_kernel, dim3(1), dim3(256), 0, stream,
                     pooled, sel_w, sel_b, fbank, combined);
  hipLaunchKernelGGL(dwconv_kernel, dim3(BB * CC, HH / TR), dim3(256), 0, stream,
                     x, combined, fb);
  hipLaunchKernelGGL(gemm_kernel, dim3(BB * 128), dim3(512), 0, stream,
                     fb, apk, proj_b, yb, part);
  hipLaunchKernelGGL(out_kernel, dim3(BB * CC), dim3(256), 0, stream,
                     x, yb, part, gamma, beta, out);
}